// Round 1
// baseline (1275.175 us; speedup 1.0000x reference)
//
#include <hip/hip_runtime.h>
#include <cstdint>
#include <cstddef>

typedef _Float16 f16;
typedef _Float16 f16x8 __attribute__((ext_vector_type(8)));
typedef float f32x4 __attribute__((ext_vector_type(4)));

#define SEQ 1024

// ---------------------------------------------------------------------------
// helpers
// ---------------------------------------------------------------------------
__device__ __forceinline__ float wave_sum64(float v) {
#pragma unroll
  for (int m = 1; m < 64; m <<= 1) v += __shfl_xor(v, m);
  return v;
}

// ---------------------------------------------------------------------------
// transpose f32 [K,N] -> f16 [N,K]   (64x64 tiles via LDS)
// ---------------------------------------------------------------------------
__global__ __launch_bounds__(256) void transpose_kernel(
    const float* __restrict__ src, f16* __restrict__ dst,
    int K, int N, long src_z, long dst_z) {
  src += (long)blockIdx.z * src_z;
  dst += (long)blockIdx.z * dst_z;
  int n0 = blockIdx.x * 64, k0 = blockIdx.y * 64;
  __shared__ float tile[64][65];
  int tid = threadIdx.x;
  int rr = tid >> 4, cc = tid & 15;
#pragma unroll
  for (int i = 0; i < 4; i++) {
    int kr = i * 16 + rr;
    float4 v = *(const float4*)(src + (long)(k0 + kr) * N + n0 + cc * 4);
    tile[kr][cc * 4 + 0] = v.x;
    tile[kr][cc * 4 + 1] = v.y;
    tile[kr][cc * 4 + 2] = v.z;
    tile[kr][cc * 4 + 3] = v.w;
  }
  __syncthreads();
#pragma unroll
  for (int i = 0; i < 4; i++) {
    int nr = i * 16 + rr;
    union { f16 h[4]; uint2 u; } cv;
#pragma unroll
    for (int j = 0; j < 4; j++) cv.h[j] = (f16)tile[cc * 4 + j][nr];
    *(uint2*)(dst + (long)(n0 + nr) * K + k0 + cc * 4) = cv.u;
  }
}

// ---------------------------------------------------------------------------
// RMSNorm: f32 [T,1024] -> f16 [T,1024]
// ---------------------------------------------------------------------------
__global__ __launch_bounds__(256) void rms_kernel(const float* __restrict__ x,
                                                  const float* __restrict__ w,
                                                  f16* __restrict__ out) {
  long t = blockIdx.x;
  int tid = threadIdx.x;
  float4 v = ((const float4*)(x + t * 1024))[tid];
  float ss = v.x * v.x + v.y * v.y + v.z * v.z + v.w * v.w;
  ss = wave_sum64(ss);
  __shared__ float sred[4];
  if ((tid & 63) == 0) sred[tid >> 6] = ss;
  __syncthreads();
  float tot = sred[0] + sred[1] + sred[2] + sred[3];
  float sc = rsqrtf(tot * (1.0f / 1024.0f) + 1e-6f);
  float4 wv = ((const float4*)w)[tid];
  union { f16 h[4]; uint2 u; } cv;
  cv.h[0] = (f16)(v.x * wv.x * sc);
  cv.h[1] = (f16)(v.y * wv.y * sc);
  cv.h[2] = (f16)(v.z * wv.z * sc);
  cv.h[3] = (f16)(v.w * wv.w * sc);
  *(uint2*)(out + t * 1024 + tid * 4) = cv.u;
}

// ---------------------------------------------------------------------------
// GEMM: C[M,N] = A[M,K] * BT[N,K]^T   (f16 in, f32 acc via MFMA 16x16x32)
// 1 wave per block, 64x64 tile, BK=32.
// MODE 0: dense, f16 out
// MODE 1: dense, f32 out = acc + addsrc
// MODE 2: dense, f32 out
// MODE 3: moe per-expert segment, A rows gathered via ptok, f16 out at poff+row
// MODE 4: moe per-expert segment, A rows direct at poff+row, f32 out scaled by pw
// ---------------------------------------------------------------------------
template <int MODE>
__global__ __launch_bounds__(64) void gemm_kernel(
    const f16* __restrict__ A, const f16* __restrict__ BT, void* __restrict__ outp,
    const float* __restrict__ addsrc, const int* __restrict__ ptok,
    const float* __restrict__ pw, const int* __restrict__ segc,
    const int* __restrict__ sego, int N, int K, long bt_estride) {
  int n0 = blockIdx.x * 64;
  int m0 = blockIdx.y * 64;
  int cnt = 1 << 30, poff = 0;
  if (MODE >= 3) {
    int e = blockIdx.z;
    cnt = segc[e];
    poff = sego[e];
    if (m0 >= cnt) return;
    BT += (long)e * bt_estride;
  }
  __shared__ f16 As[64][72];
  __shared__ f16 Bs[64][72];
  int lane = threadIdx.x;
  const f16* arow;
  if (MODE == 3) {
    int r = m0 + lane;
    if (r >= cnt) r = cnt - 1;
    arow = A + (long)ptok[poff + r] * K;
  } else if (MODE == 4) {
    int r = m0 + lane;
    if (r >= cnt) r = cnt - 1;
    arow = A + (long)(poff + r) * K;
  } else {
    arow = A + (long)(m0 + lane) * K;
  }
  const f16* brow = BT + (long)(n0 + lane) * K;

  f32x4 acc[4][4] = {};
  int quad = lane >> 4, l16 = lane & 15;

  for (int k0 = 0; k0 < K; k0 += 32) {
    uint4 av[4], bv[4];
#pragma unroll
    for (int s = 0; s < 4; s++) {
      av[s] = *(const uint4*)(arow + k0 + s * 8);
      bv[s] = *(const uint4*)(brow + k0 + s * 8);
    }
    __syncthreads();
#pragma unroll
    for (int s = 0; s < 4; s++) {
      *(uint4*)&As[lane][s * 8] = av[s];
      *(uint4*)&Bs[lane][s * 8] = bv[s];
    }
    __syncthreads();
    f16x8 af[4], bf[4];
#pragma unroll
    for (int i = 0; i < 4; i++) af[i] = *(const f16x8*)&As[i * 16 + l16][quad * 8];
#pragma unroll
    for (int j = 0; j < 4; j++) bf[j] = *(const f16x8*)&Bs[j * 16 + l16][quad * 8];
#pragma unroll
    for (int i = 0; i < 4; i++)
#pragma unroll
      for (int j = 0; j < 4; j++)
        acc[i][j] = __builtin_amdgcn_mfma_f32_16x16x32_f16(af[i], bf[j], acc[i][j], 0, 0, 0);
  }

#pragma unroll
  for (int i = 0; i < 4; i++) {
#pragma unroll
    for (int j = 0; j < 4; j++) {
      int col = n0 + j * 16 + l16;
#pragma unroll
      for (int r = 0; r < 4; r++) {
        int row = m0 + i * 16 + quad * 4 + r;
        float v = acc[i][j][r];
        if (MODE == 0) {
          ((f16*)outp)[(long)row * N + col] = (f16)v;
        } else if (MODE == 1) {
          ((float*)outp)[(long)row * N + col] = v + addsrc[(long)row * N + col];
        } else if (MODE == 2) {
          ((float*)outp)[(long)row * N + col] = v;
        } else if (MODE == 3) {
          if (row < cnt) ((f16*)outp)[(long)(poff + row) * N + col] = (f16)v;
        } else {
          if (row < cnt) ((float*)outp)[(long)(poff + row) * N + col] = v * pw[poff + row];
        }
      }
    }
  }
}

// ---------------------------------------------------------------------------
// RoPE in-place on qkv f16 [T,1536]: q cols 0..1023 (16 heads), k cols 1024..1279
// ---------------------------------------------------------------------------
__global__ __launch_bounds__(256) void rope_kernel(f16* __restrict__ qkv,
                                                   const int* __restrict__ pos_ids) {
  int idx = blockIdx.x * 256 + threadIdx.x;  // T*20*32 = 1310720 exactly
  int i = idx & 31;
  int r2 = idx >> 5;
  int hh = r2 % 20;
  int t = r2 / 20;
  int pos = pos_ids[t];
  float f = (float)pos * expf((float)i * (-13.815510557964274f / 32.0f));
  float sv, cv;
  sincosf(f, &sv, &cv);
  int col = (hh < 16) ? (hh * 64 + i) : (1024 + (hh - 16) * 64 + i);
  f16* p = qkv + (long)t * 1536 + col;
  float x1 = (float)p[0], x2 = (float)p[32];
  p[0] = (f16)(x1 * cv - x2 * sv);
  p[32] = (f16)(x2 * cv + x1 * sv);
}

// ---------------------------------------------------------------------------
// flash-style attention (scalar fp32 math, f16 I/O)
// grid (B*NH=32, S/64=16), block 256. GQA: kv head = h>>2.
// qkv layout per token row (1536): [q 16*64][k 4*64][v 4*64]
// ---------------------------------------------------------------------------
__global__ __launch_bounds__(256) void attn_kernel(const f16* __restrict__ qkv,
                                                   f16* __restrict__ aout) {
  int bh = blockIdx.x;
  int b = bh >> 4, h = bh & 15;
  int kvh = h >> 2;
  int qt = blockIdx.y;
  int q0 = qt * 64;
  int tid = threadIdx.x;
  __shared__ float qs[64][68];
  __shared__ float ks[64][68];  // re-used as P after score phase
  __shared__ float vs[64][68];
  {
    int row = tid >> 2, ds = (tid & 3) * 16;
    const f16* src = qkv + (long)(b * SEQ + q0 + row) * 1536 + h * 64 + ds;
    union { uint4 u; f16 hh[8]; } u0, u1;
    u0.u = *(const uint4*)src;
    u1.u = *(const uint4*)(src + 8);
#pragma unroll
    for (int j = 0; j < 8; j++) {
      qs[row][ds + j] = (float)u0.hh[j];
      qs[row][ds + 8 + j] = (float)u1.hh[j];
    }
  }
  int rp = tid >> 3, c = tid & 7;
  int r0 = 2 * rp, r1 = 2 * rp + 1;
  float mr0 = -1e30f, mr1 = -1e30f, l0 = 0.f, l1 = 0.f;
  float o0[8], o1[8];
#pragma unroll
  for (int d = 0; d < 8; d++) { o0[d] = 0.f; o1[d] = 0.f; }

  for (int kt = 0; kt <= qt; kt++) {
    __syncthreads();  // previous PV phase done before restaging
    {
      int row = tid >> 2, ds = (tid & 3) * 16;
      const f16* ksrc = qkv + (long)(b * SEQ + kt * 64 + row) * 1536 + 1024 + kvh * 64 + ds;
      union { uint4 u; f16 hh[8]; } a0, a1, b0, b1;
      a0.u = *(const uint4*)ksrc;
      a1.u = *(const uint4*)(ksrc + 8);
      b0.u = *(const uint4*)(ksrc + 256);
      b1.u = *(const uint4*)(ksrc + 264);
#pragma unroll
      for (int j = 0; j < 8; j++) {
        ks[row][ds + j] = (float)a0.hh[j];
        ks[row][ds + 8 + j] = (float)a1.hh[j];
        vs[row][ds + j] = (float)b0.hh[j];
        vs[row][ds + 8 + j] = (float)b1.hh[j];
      }
    }
    __syncthreads();
    float s0[8], s1[8];
#pragma unroll
    for (int jj = 0; jj < 8; jj++) { s0[jj] = 0.f; s1[jj] = 0.f; }
    for (int d4 = 0; d4 < 16; d4++) {
      float4 qa = *(const float4*)&qs[r0][d4 * 4];
      float4 qb = *(const float4*)&qs[r1][d4 * 4];
#pragma unroll
      for (int jj = 0; jj < 8; jj++) {
        float4 kk = *(const float4*)&ks[c * 8 + jj][d4 * 4];
        s0[jj] += qa.x * kk.x + qa.y * kk.y + qa.z * kk.z + qa.w * kk.w;
        s1[jj] += qb.x * kk.x + qb.y * kk.y + qb.z * kk.z + qb.w * kk.w;
      }
    }
    float mx0 = -1e30f, mx1 = -1e30f;
#pragma unroll
    for (int jj = 0; jj < 8; jj++) {
      int kg = kt * 64 + c * 8 + jj;
      s0[jj] = (kg <= q0 + r0) ? s0[jj] * 0.125f : -1e30f;
      s1[jj] = (kg <= q0 + r1) ? s1[jj] * 0.125f : -1e30f;
      mx0 = fmaxf(mx0, s0[jj]);
      mx1 = fmaxf(mx1, s1[jj]);
    }
    mx0 = fmaxf(mx0, __shfl_xor(mx0, 1));
    mx0 = fmaxf(mx0, __shfl_xor(mx0, 2));
    mx0 = fmaxf(mx0, __shfl_xor(mx0, 4));
    mx1 = fmaxf(mx1, __shfl_xor(mx1, 1));
    mx1 = fmaxf(mx1, __shfl_xor(mx1, 2));
    mx1 = fmaxf(mx1, __shfl_xor(mx1, 4));
    float mn0 = fmaxf(mr0, mx0), mn1 = fmaxf(mr1, mx1);
    float al0 = expf(mr0 - mn0), al1 = expf(mr1 - mn1);
    float sum0 = 0.f, sum1 = 0.f;
#pragma unroll
    for (int jj = 0; jj < 8; jj++) {
      s0[jj] = expf(s0[jj] - mn0);
      sum0 += s0[jj];
      s1[jj] = expf(s1[jj] - mn1);
      sum1 += s1[jj];
    }
    sum0 += __shfl_xor(sum0, 1); sum0 += __shfl_xor(sum0, 2); sum0 += __shfl_xor(sum0, 4);
    sum1 += __shfl_xor(sum1, 1); sum1 += __shfl_xor(sum1, 2); sum1 += __shfl_xor(sum1, 4);
    l0 = l0 * al0 + sum0;
    l1 = l1 * al1 + sum1;
#pragma unroll
    for (int d = 0; d < 8; d++) { o0[d] *= al0; o1[d] *= al1; }
    mr0 = mn0;
    mr1 = mn1;
    __syncthreads();  // everyone done reading ks before P overwrite
#pragma unroll
    for (int jj = 0; jj < 8; jj++) {
      ks[r0][c * 8 + jj] = s0[jj];
      ks[r1][c * 8 + jj] = s1[jj];
    }
    __syncthreads();
    for (int j = 0; j < 64; j++) {
      float pa = ks[r0][j], pb = ks[r1][j];
      float4 va = *(const float4*)&vs[j][c * 8];
      float4 vb = *(const float4*)&vs[j][c * 8 + 4];
      o0[0] += pa * va.x; o0[1] += pa * va.y; o0[2] += pa * va.z; o0[3] += pa * va.w;
      o0[4] += pa * vb.x; o0[5] += pa * vb.y; o0[6] += pa * vb.z; o0[7] += pa * vb.w;
      o1[0] += pb * va.x; o1[1] += pb * va.y; o1[2] += pb * va.z; o1[3] += pb * va.w;
      o1[4] += pb * vb.x; o1[5] += pb * vb.y; o1[6] += pb * vb.z; o1[7] += pb * vb.w;
    }
  }
  float iv0 = 1.0f / l0, iv1 = 1.0f / l1;
  f16* d0 = aout + (long)(b * SEQ + q0 + r0) * 1024 + h * 64 + c * 8;
  f16* d1 = aout + (long)(b * SEQ + q0 + r1) * 1024 + h * 64 + c * 8;
  union { f16 hh[4]; uint2 u; } w;
  w.hh[0] = (f16)(o0[0] * iv0); w.hh[1] = (f16)(o0[1] * iv0);
  w.hh[2] = (f16)(o0[2] * iv0); w.hh[3] = (f16)(o0[3] * iv0);
  *(uint2*)d0 = w.u;
  w.hh[0] = (f16)(o0[4] * iv0); w.hh[1] = (f16)(o0[5] * iv0);
  w.hh[2] = (f16)(o0[6] * iv0); w.hh[3] = (f16)(o0[7] * iv0);
  *(uint2*)(d0 + 4) = w.u;
  w.hh[0] = (f16)(o1[0] * iv1); w.hh[1] = (f16)(o1[1] * iv1);
  w.hh[2] = (f16)(o1[2] * iv1); w.hh[3] = (f16)(o1[3] * iv1);
  *(uint2*)d1 = w.u;
  w.hh[0] = (f16)(o1[4] * iv1); w.hh[1] = (f16)(o1[5] * iv1);
  w.hh[2] = (f16)(o1[6] * iv1); w.hh[3] = (f16)(o1[7] * iv1);
  *(uint2*)(d1 + 4) = w.u;
}

// ---------------------------------------------------------------------------
// router: full-f32 logits from resid (own RMS) -> softmax -> top2 + prob sums
// one wave per token; grid 512 x 256
// ---------------------------------------------------------------------------
__global__ __launch_bounds__(256) void router_kernel(
    const float* __restrict__ resid, const float* __restrict__ ln2w,
    const float* __restrict__ rw, int* __restrict__ topi, float* __restrict__ topw,
    float* __restrict__ psum) {
  int t = blockIdx.x * 4 + (threadIdx.x >> 6);
  int lane = threadIdx.x & 63;
  const float* x = resid + (long)t * 1024;
  float ss = 0.f;
  for (int h = lane; h < 1024; h += 64) {
    float v = x[h];
    ss += v * v;
  }
  ss = wave_sum64(ss);
  float sc = rsqrtf(ss * (1.0f / 1024.0f) + 1e-6f);
  float acc[8] = {0.f, 0.f, 0.f, 0.f, 0.f, 0.f, 0.f, 0.f};
  for (int h = lane; h < 1024; h += 64) {
    float xn = x[h] * sc * ln2w[h];
    const float4* r4 = (const float4*)(rw + h * 8);
    float4 ra = r4[0], rb = r4[1];
    acc[0] += xn * ra.x; acc[1] += xn * ra.y; acc[2] += xn * ra.z; acc[3] += xn * ra.w;
    acc[4] += xn * rb.x; acc[5] += xn * rb.y; acc[6] += xn * rb.z; acc[7] += xn * rb.w;
  }
#pragma unroll
  for (int m = 1; m < 64; m <<= 1) {
#pragma unroll
    for (int e = 0; e < 8; e++) acc[e] += __shfl_xor(acc[e], m);
  }
  if (lane == 0) {
    float mx = acc[0];
#pragma unroll
    for (int e = 1; e < 8; e++) mx = fmaxf(mx, acc[e]);
    float p[8];
    float s = 0.f;
#pragma unroll
    for (int e = 0; e < 8; e++) {
      p[e] = expf(acc[e] - mx);
      s += p[e];
    }
    float inv = 1.0f / s;
#pragma unroll
    for (int e = 0; e < 8; e++) {
      p[e] *= inv;
      atomicAdd(&psum[e], p[e]);
    }
    int i1 = 0;
    float b1 = p[0];
#pragma unroll
    for (int e = 1; e < 8; e++)
      if (p[e] > b1) { b1 = p[e]; i1 = e; }
    int i2 = -1;
    float b2 = -1.f;
#pragma unroll
    for (int e = 0; e < 8; e++)
      if (e != i1 && p[e] > b2) { b2 = p[e]; i2 = e; }
    topi[2 * t] = i1;
    topi[2 * t + 1] = i2;
    topw[2 * t] = b1;
    topw[2 * t + 1] = b2;
  }
}

// ---------------------------------------------------------------------------
// compact pairs by expert (single block) + aux output
// ---------------------------------------------------------------------------
__global__ __launch_bounds__(256) void compact_kernel(
    const int* __restrict__ topi, const float* __restrict__ topw, int* __restrict__ segc,
    int* __restrict__ sego, int* __restrict__ ptok, float* __restrict__ pw,
    int* __restrict__ tslot, const float* __restrict__ psum, float* __restrict__ aux_out) {
  __shared__ int c[8];
  __shared__ int off[9];
  __shared__ int cur[8];
  int tid = threadIdx.x;
  if (tid < 8) { c[tid] = 0; cur[tid] = 0; }
  __syncthreads();
  for (int i = tid; i < 4096; i += 256) atomicAdd(&c[topi[i]], 1);
  __syncthreads();
  if (tid == 0) {
    off[0] = 0;
    for (int e = 0; e < 8; e++) off[e + 1] = off[e] + c[e];
  }
  __syncthreads();
  for (int i = tid; i < 4096; i += 256) {
    int e = topi[i];
    int pidx = atomicAdd(&cur[e], 1);
    int slot = off[e] + pidx;
    ptok[slot] = i >> 1;
    pw[slot] = topw[i];
    tslot[i] = slot;
  }
  if (tid < 8) {
    segc[tid] = c[tid];
    sego[tid] = off[tid];
  }
  if (tid == 0) {
    float a = 0.f;
    for (int e = 0; e < 8; e++) {
      float d = psum[e] * (1.0f / 2048.0f) - 0.125f;
      a += d * d;
    }
    aux_out[0] = a * (1.0f / 8.0f);
  }
}

// ---------------------------------------------------------------------------
// silu(gate)*up on [rows, 2048] -> [rows, 1024]
// ---------------------------------------------------------------------------
__global__ __launch_bounds__(256) void silu_kernel(const f16* __restrict__ gu,
                                                   f16* __restrict__ act, int rows) {
  int id = blockIdx.x * 256 + threadIdx.x;
  int base = id * 4;
  int row = base >> 10;
  int i = base & 1023;
  if (row >= rows) return;
  union { uint2 u; f16 h[4]; } G, U, O;
  G.u = *(const uint2*)(gu + (long)row * 2048 + i);
  U.u = *(const uint2*)(gu + (long)row * 2048 + 1024 + i);
#pragma unroll
  for (int j = 0; j < 4; j++) {
    float g = (float)G.h[j];
    float u = (float)U.h[j];
    O.h[j] = (f16)(g / (1.0f + expf(-g)) * u);
  }
  *(uint2*)(act + (long)row * 1024 + i) = O.u;
}

// ---------------------------------------------------------------------------
// sgate = sigmoid(x2 . w); one wave per token
// ---------------------------------------------------------------------------
__global__ __launch_bounds__(256) void sgate_kernel(const f16* __restrict__ x2,
                                                    const float* __restrict__ gw,
                                                    float* __restrict__ sg) {
  int t = blockIdx.x * 4 + (threadIdx.x >> 6);
  int lane = threadIdx.x & 63;
  const f16* x = x2 + (long)t * 1024;
  float acc = 0.f;
  for (int h = lane; h < 1024; h += 64) acc += (float)x[h] * gw[h];
  acc = wave_sum64(acc);
  if (lane == 0) sg[t] = 1.0f / (1.0f + expf(-acc));
}

// ---------------------------------------------------------------------------
// final: out = resid + sgate*shared + y[slot0] + y[slot1]
// ---------------------------------------------------------------------------
__global__ __launch_bounds__(256) void final_kernel(
    const float* __restrict__ resid, const float* __restrict__ sh,
    const float* __restrict__ sg, const float* __restrict__ ybuf,
    const int* __restrict__ tslot, float* __restrict__ out) {
  int t = blockIdx.x;
  int tid = threadIdx.x;
  int s0 = tslot[2 * t], s1 = tslot[2 * t + 1];
  float g = sg[t];
  float4 a = ((const float4*)(resid + (long)t * 1024))[tid];
  float4 b = ((const float4*)(sh + (long)t * 1024))[tid];
  float4 c0 = ((const float4*)(ybuf + (long)s0 * 1024))[tid];
  float4 c1 = ((const float4*)(ybuf + (long)s1 * 1024))[tid];
  float4 o;
  o.x = a.x + g * b.x + c0.x + c1.x;
  o.y = a.y + g * b.y + c0.y + c1.y;
  o.z = a.z + g * b.z + c0.z + c1.z;
  o.w = a.w + g * b.w + c0.w + c1.w;
  ((float4*)(out + (long)t * 1024))[tid] = o;
}

// ---------------------------------------------------------------------------
extern "C" void kernel_launch(void* const* d_in, const int* in_sizes, int n_in,
                              void* d_out, int out_size, void* d_ws, size_t ws_size,
                              hipStream_t stream) {
  const float* hidden = (const float*)d_in[0];
  // d_in[1] attention_mask: exactly causal -1e9; applied analytically
  const int* pos_ids = (const int*)d_in[2];
  const float* ln1w = (const float*)d_in[3];
  const float* ln2w = (const float*)d_in[4];
  const float* wq = (const float*)d_in[5];
  const float* wk = (const float*)d_in[6];
  const float* wv = (const float*)d_in[7];
  const float* wo = (const float*)d_in[8];
  const float* router_w = (const float*)d_in[9];
  const float* egw = (const float*)d_in[10];
  const float* euw = (const float*)d_in[11];
  const float* edw = (const float*)d_in[12];
  const float* sgw = (const float*)d_in[13];
  const float* suw = (const float*)d_in[14];
  const float* sdw = (const float*)d_in[15];
  const float* segw = (const float*)d_in[16];
  float* out = (float*)d_out;

  char* p = (char*)d_ws;
  auto alloc = [&](size_t bytes) {
    char* r = p;
    p += (bytes + 255) & ~(size_t)255;
    return r;
  };
  f16* wqkvT = (f16*)alloc(1536l * 1024 * 2);
  f16* woT = (f16*)alloc(1024l * 1024 * 2);
  f16* sguT = (f16*)alloc(2048l * 1024 * 2);
  f16* sdT = (f16*)alloc(1024l * 1024 * 2);
  f16* guT = (f16*)alloc(8l * 2048 * 1024 * 2);
  f16* dnT = (f16*)alloc(8l * 1024 * 1024 * 2);
  f16* xln1 = (f16*)alloc(2048l * 1024 * 2);
  f16* qkv = (f16*)alloc(2048l * 1536 * 2);
  f16* attnO = (f16*)alloc(2048l * 1024 * 2);
  float* resid = (float*)alloc(2048l * 1024 * 4);
  f16* x2 = (f16*)alloc(2048l * 1024 * 2);
  f16* gs_us = (f16*)alloc(2048l * 2048 * 2);
  f16* act_s = (f16*)alloc(2048l * 1024 * 2);
  float* sh_out = (float*)alloc(2048l * 1024 * 4);
  f16* gu_r = (f16*)alloc(4096l * 2048 * 2);
  f16* act_r = (f16*)alloc(4096l * 1024 * 2);
  float* ybuf = (float*)alloc(4096l * 1024 * 4);
  float* sgate = (float*)alloc(2048 * 4);
  int* topi = (int*)alloc(4096 * 4);
  float* topw = (float*)alloc(4096 * 4);
  int* ptok = (int*)alloc(4096 * 4);
  float* pwts = (float*)alloc(4096 * 4);
  int* tslot = (int*)alloc(4096 * 4);
  int* segc = (int*)alloc(8 * 4);
  int* sego = (int*)alloc(8 * 4);
  float* psum = (float*)alloc(8 * 4);

  hipMemsetAsync(psum, 0, 8 * sizeof(float), stream);

  // weight transposes f32[K,N] -> f16[N,K]
  transpose_kernel<<<dim3(16, 16, 1), 256, 0, stream>>>(wq, wqkvT, 1024, 1024, 0, 0);
  transpose_kernel<<<dim3(4, 16, 1), 256, 0, stream>>>(wk, wqkvT + 1024l * 1024, 1024, 256, 0, 0);
  transpose_kernel<<<dim3(4, 16, 1), 256, 0, stream>>>(wv, wqkvT + 1280l * 1024, 1024, 256, 0, 0);
  transpose_kernel<<<dim3(16, 16, 1), 256, 0, stream>>>(wo, woT, 1024, 1024, 0, 0);
  transpose_kernel<<<dim3(16, 16, 1), 256, 0, stream>>>(sgw, sguT, 1024, 1024, 0, 0);
  transpose_kernel<<<dim3(16, 16, 1), 256, 0, stream>>>(suw, sguT + 1024l * 1024, 1024, 1024, 0, 0);
  transpose_kernel<<<dim3(16, 16, 1), 256, 0, stream>>>(sdw, sdT, 1024, 1024, 0, 0);
  transpose_kernel<<<dim3(16, 16, 8), 256, 0, stream>>>(egw, guT, 1024, 1024, 1024l * 1024, 2048l * 1024);
  transpose_kernel<<<dim3(16, 16, 8), 256, 0, stream>>>(euw, guT + 1024l * 1024, 1024, 1024, 1024l * 1024, 2048l * 1024);
  transpose_kernel<<<dim3(16, 16, 8), 256, 0, stream>>>(edw, dnT, 1024, 1024, 1024l * 1024, 1024l * 1024);

  // attention path
  rms_kernel<<<2048, 256, 0, stream>>>(hidden, ln1w, xln1);
  gemm_kernel<0><<<dim3(24, 32, 1), 64, 0, stream>>>(xln1, wqkvT, qkv, nullptr, nullptr, nullptr, nullptr, nullptr, 1536, 1024, 0);
  rope_kernel<<<5120, 256, 0, stream>>>(qkv, pos_ids);
  attn_kernel<<<dim3(32, 16, 1), 256, 0, stream>>>(qkv, attnO);
  gemm_kernel<1><<<dim3(16, 32, 1), 64, 0, stream>>>(attnO, woT, resid, hidden, nullptr, nullptr, nullptr, nullptr, 1024, 1024, 0);

  // MoE path
  rms_kernel<<<2048, 256, 0, stream>>>(resid, ln2w, x2);
  router_kernel<<<512, 256, 0, stream>>>(resid, ln2w, router_w, topi, topw, psum);
  compact_kernel<<<1, 256, 0, stream>>>(topi, topw, segc, sego, ptok, pwts, tslot, psum, out + 2097152);

  gemm_kernel<0><<<dim3(32, 32, 1), 64, 0, stream>>>(x2, sguT, gs_us, nullptr, nullptr, nullptr, nullptr, nullptr, 2048, 1024, 0);
  silu_kernel<<<2048, 256, 0, stream>>>(gs_us, act_s, 2048);
  gemm_kernel<2><<<dim3(16, 32, 1), 64, 0, stream>>>(act_s, sdT, sh_out, nullptr, nullptr, nullptr, nullptr, nullptr, 1024, 1024, 0);
  sgate_kernel<<<512, 256, 0, stream>>>(x2, segw, sgate);

  gemm_kernel<3><<<dim3(32, 32, 8), 64, 0, stream>>>(x2, guT, gu_r, nullptr, ptok, nullptr, segc, sego, 2048, 1024, 2048l * 1024);
  silu_kernel<<<4096, 256, 0, stream>>>(gu_r, act_r, 4096);
  gemm_kernel<4><<<dim3(16, 32, 8), 64, 0, stream>>>(act_r, dnT, ybuf, nullptr, nullptr, pwts, segc, sego, 1024, 1024, 1024l * 1024);

  final_kernel<<<2048, 256, 0, stream>>>(resid, sh_out, sgate, ybuf, tslot, out);
}

// Round 2
// 800.184 us; speedup vs baseline: 1.5936x; 1.5936x over previous
//
#include <hip/hip_runtime.h>
#include <cstdint>
#include <cstddef>

typedef _Float16 f16;
typedef _Float16 f16x8 __attribute__((ext_vector_type(8)));
typedef float f32x4 __attribute__((ext_vector_type(4)));

#define SEQ 1024

// ---------------------------------------------------------------------------
// helpers
// ---------------------------------------------------------------------------
__device__ __forceinline__ float wave_sum64(float v) {
#pragma unroll
  for (int m = 1; m < 64; m <<= 1) v += __shfl_xor(v, m);
  return v;
}

// ---------------------------------------------------------------------------
// transpose f32 [K,N] -> f16 [N,K]   (64x64 tiles via LDS)
// ---------------------------------------------------------------------------
__global__ __launch_bounds__(256) void transpose_kernel(
    const float* __restrict__ src, f16* __restrict__ dst,
    int K, int N, long src_z, long dst_z) {
  src += (long)blockIdx.z * src_z;
  dst += (long)blockIdx.z * dst_z;
  int n0 = blockIdx.x * 64, k0 = blockIdx.y * 64;
  __shared__ float tile[64][65];
  int tid = threadIdx.x;
  int rr = tid >> 4, cc = tid & 15;
#pragma unroll
  for (int i = 0; i < 4; i++) {
    int kr = i * 16 + rr;
    float4 v = *(const float4*)(src + (long)(k0 + kr) * N + n0 + cc * 4);
    tile[kr][cc * 4 + 0] = v.x;
    tile[kr][cc * 4 + 1] = v.y;
    tile[kr][cc * 4 + 2] = v.z;
    tile[kr][cc * 4 + 3] = v.w;
  }
  __syncthreads();
#pragma unroll
  for (int i = 0; i < 4; i++) {
    int nr = i * 16 + rr;
    union { f16 h[4]; uint2 u; } cv;
#pragma unroll
    for (int j = 0; j < 4; j++) cv.h[j] = (f16)tile[cc * 4 + j][nr];
    *(uint2*)(dst + (long)(n0 + nr) * K + k0 + cc * 4) = cv.u;
  }
}

// ---------------------------------------------------------------------------
// RMSNorm: f32 [T,1024] -> f16 [T,1024]
// ---------------------------------------------------------------------------
__global__ __launch_bounds__(256) void rms_kernel(const float* __restrict__ x,
                                                  const float* __restrict__ w,
                                                  f16* __restrict__ out) {
  long t = blockIdx.x;
  int tid = threadIdx.x;
  float4 v = ((const float4*)(x + t * 1024))[tid];
  float ss = v.x * v.x + v.y * v.y + v.z * v.z + v.w * v.w;
  ss = wave_sum64(ss);
  __shared__ float sred[4];
  if ((tid & 63) == 0) sred[tid >> 6] = ss;
  __syncthreads();
  float tot = sred[0] + sred[1] + sred[2] + sred[3];
  float sc = rsqrtf(tot * (1.0f / 1024.0f) + 1e-6f);
  float4 wv = ((const float4*)w)[tid];
  union { f16 h[4]; uint2 u; } cv;
  cv.h[0] = (f16)(v.x * wv.x * sc);
  cv.h[1] = (f16)(v.y * wv.y * sc);
  cv.h[2] = (f16)(v.z * wv.z * sc);
  cv.h[3] = (f16)(v.w * wv.w * sc);
  *(uint2*)(out + t * 1024 + tid * 4) = cv.u;
}

// ---------------------------------------------------------------------------
// GEMM: C[M,N] = A[M,K] * BT[N,K]^T   (f16 in, f32 acc via MFMA 16x16x32)
// 256 threads (4 waves), 128x128 tile, BK=64, global_load_lds(16B) staging
// with XOR-swizzled LDS placement (per-lane global addr permutation) so
// ds_read_b128 fragment reads are 2-way (free) instead of 8/16-way.
// MODE 0: dense, f16 out (LDS-transposed coalesced stores)
// MODE 1: dense, f32 out = acc + addsrc
// MODE 2: dense, f32 out
// MODE 3: moe segment, A rows gathered via ptok, f16 out at poff+row
// MODE 4: moe segment, A rows direct at poff+row, f32 out scaled by pw
// ---------------------------------------------------------------------------
template <int MODE>
__global__ __launch_bounds__(256) void gemm_kernel(
    const f16* __restrict__ A, const f16* __restrict__ BT, void* __restrict__ outp,
    const float* __restrict__ addsrc, const int* __restrict__ ptok,
    const float* __restrict__ pw, const int* __restrict__ segc,
    const int* __restrict__ sego, int N, int K, long bt_estride) {
  int n0 = blockIdx.x * 128;
  int m0 = blockIdx.y * 128;
  int cnt = 1 << 30, poff = 0;
  if (MODE >= 3) {
    int e = blockIdx.z;
    cnt = segc[e];
    poff = sego[e];
    if (cnt == 0 || m0 >= cnt) return;
    BT += (long)e * bt_estride;
  }
  // staging: As [128 rows][64 k] f16 (8 chunks of 16B per row, swizzled pos),
  //          Bs same, total 32 KB. Epilogue (f16 modes) reuses all 32 KB as
  //          C tile [128][128] f16.
  __shared__ f16 smem[16384];
  f16* As = smem;
  f16* Bs = smem + 8192;
  int tid = threadIdx.x;
  int w = tid >> 6, lane = tid & 63;
  int quad = lane >> 4, l16 = lane & 15;
  int wm = (w >> 1) * 64, wn = (w & 1) * 64;

  // per-lane staging pointers: chunk c = i*256+tid; stored LDS pos kp=c&7 of
  // row r=c>>3 holds GLOBAL chunk kq = kp ^ (r&7).
  const f16* agp[4];
  const f16* bgp[4];
#pragma unroll
  for (int i = 0; i < 4; i++) {
    int c = i * 256 + tid;
    int r = c >> 3;
    int kq = (c & 7) ^ (r & 7);
    int ar = m0 + r;
    if (MODE == 3) {
      int rr = ar < cnt ? ar : cnt - 1;
      agp[i] = A + (long)ptok[poff + rr] * K + kq * 8;
    } else if (MODE == 4) {
      int rr = ar < cnt ? ar : cnt - 1;
      agp[i] = A + (long)(poff + rr) * K + kq * 8;
    } else {
      agp[i] = A + (long)ar * K + kq * 8;
    }
    bgp[i] = BT + (long)(n0 + r) * K + kq * 8;
  }

  f32x4 acc[4][4] = {};

  for (int k0 = 0; k0 < K; k0 += 64) {
    __syncthreads();  // previous compute done reading LDS
#pragma unroll
    for (int i = 0; i < 4; i++) {
      __builtin_amdgcn_global_load_lds(
          (const __attribute__((address_space(1))) void*)(agp[i] + k0),
          (__attribute__((address_space(3))) void*)(As + (i * 256 + w * 64) * 8),
          16, 0, 0);
      __builtin_amdgcn_global_load_lds(
          (const __attribute__((address_space(1))) void*)(bgp[i] + k0),
          (__attribute__((address_space(3))) void*)(Bs + (i * 256 + w * 64) * 8),
          16, 0, 0);
    }
    __syncthreads();  // vmcnt(0) drain: staged data visible
#pragma unroll
    for (int kk = 0; kk < 2; kk++) {
      f16x8 af[4], bf[4];
      int q = kk * 4 + quad;
#pragma unroll
      for (int i = 0; i < 4; i++) {
        int ra = wm + i * 16 + l16;
        af[i] = *(const f16x8*)&As[ra * 64 + (q ^ (ra & 7)) * 8];
        int rb = wn + i * 16 + l16;
        bf[i] = *(const f16x8*)&Bs[rb * 64 + (q ^ (rb & 7)) * 8];
      }
#pragma unroll
      for (int i = 0; i < 4; i++)
#pragma unroll
        for (int j = 0; j < 4; j++)
          acc[i][j] = __builtin_amdgcn_mfma_f32_16x16x32_f16(af[i], bf[j], acc[i][j], 0, 0, 0);
    }
  }

  if (MODE == 1 || MODE == 2 || MODE == 4) {
    // f32 out: 16 lanes x 4B = 64B contiguous per store, already coalesced
#pragma unroll
    for (int i = 0; i < 4; i++) {
#pragma unroll
      for (int j = 0; j < 4; j++) {
        int col = n0 + wn + j * 16 + l16;
#pragma unroll
        for (int r = 0; r < 4; r++) {
          int row = m0 + wm + i * 16 + quad * 4 + r;
          float v = acc[i][j][r];
          if (MODE == 1) {
            ((float*)outp)[(long)row * N + col] = v + addsrc[(long)row * N + col];
          } else if (MODE == 2) {
            ((float*)outp)[(long)row * N + col] = v;
          } else {
            if (row < cnt) ((float*)outp)[(long)(poff + row) * N + col] = v * pw[poff + row];
          }
        }
      }
    }
  } else {
    // f16 out: transpose through LDS for 16B/lane coalesced stores
    __syncthreads();
#pragma unroll
    for (int i = 0; i < 4; i++)
#pragma unroll
      for (int j = 0; j < 4; j++)
#pragma unroll
        for (int r = 0; r < 4; r++) {
          int lr = wm + i * 16 + quad * 4 + r;
          int lc = wn + j * 16 + l16;
          smem[lr * 128 + lc] = (f16)acc[i][j][r];
        }
    __syncthreads();
#pragma unroll
    for (int ii = 0; ii < 8; ii++) {
      int c = ii * 256 + tid;  // 2048 chunks of 16B
      int row = c >> 4, off = (c & 15) * 8;
      uint4 v = *(const uint4*)&smem[row * 128 + off];
      int grow = m0 + row;
      if (MODE == 0) {
        *(uint4*)&((f16*)outp)[(long)grow * N + n0 + off] = v;
      } else {
        if (grow < cnt) *(uint4*)&((f16*)outp)[(long)(poff + grow) * N + n0 + off] = v;
      }
    }
  }
}

// ---------------------------------------------------------------------------
// RoPE in-place on qkv f16 [T,1536]: q cols 0..1023 (16 heads), k cols 1024..1279
// ---------------------------------------------------------------------------
__global__ __launch_bounds__(256) void rope_kernel(f16* __restrict__ qkv,
                                                   const int* __restrict__ pos_ids) {
  int idx = blockIdx.x * 256 + threadIdx.x;  // T*20*32 = 1310720 exactly
  int i = idx & 31;
  int r2 = idx >> 5;
  int hh = r2 % 20;
  int t = r2 / 20;
  int pos = pos_ids[t];
  float f = (float)pos * expf((float)i * (-13.815510557964274f / 32.0f));
  float sv, cv;
  sincosf(f, &sv, &cv);
  int col = (hh < 16) ? (hh * 64 + i) : (1024 + (hh - 16) * 64 + i);
  f16* p = qkv + (long)t * 1536 + col;
  float x1 = (float)p[0], x2 = (float)p[32];
  p[0] = (f16)(x1 * cv - x2 * sv);
  p[32] = (f16)(x2 * cv + x1 * sv);
}

// ---------------------------------------------------------------------------
// flash-style attention (scalar fp32 math, f16 I/O)
// grid (B*NH=32, S/64=16), block 256. GQA: kv head = h>>2.
// qkv layout per token row (1536): [q 16*64][k 4*64][v 4*64]
// ---------------------------------------------------------------------------
__global__ __launch_bounds__(256) void attn_kernel(const f16* __restrict__ qkv,
                                                   f16* __restrict__ aout) {
  int bh = blockIdx.x;
  int b = bh >> 4, h = bh & 15;
  int kvh = h >> 2;
  int qt = blockIdx.y;
  int q0 = qt * 64;
  int tid = threadIdx.x;
  __shared__ float qs[64][68];
  __shared__ float ks[64][68];  // re-used as P after score phase
  __shared__ float vs[64][68];
  {
    int row = tid >> 2, ds = (tid & 3) * 16;
    const f16* src = qkv + (long)(b * SEQ + q0 + row) * 1536 + h * 64 + ds;
    union { uint4 u; f16 hh[8]; } u0, u1;
    u0.u = *(const uint4*)src;
    u1.u = *(const uint4*)(src + 8);
#pragma unroll
    for (int j = 0; j < 8; j++) {
      qs[row][ds + j] = (float)u0.hh[j];
      qs[row][ds + 8 + j] = (float)u1.hh[j];
    }
  }
  int rp = tid >> 3, c = tid & 7;
  int r0 = 2 * rp, r1 = 2 * rp + 1;
  float mr0 = -1e30f, mr1 = -1e30f, l0 = 0.f, l1 = 0.f;
  float o0[8], o1[8];
#pragma unroll
  for (int d = 0; d < 8; d++) { o0[d] = 0.f; o1[d] = 0.f; }

  for (int kt = 0; kt <= qt; kt++) {
    __syncthreads();  // previous PV phase done before restaging
    {
      int row = tid >> 2, ds = (tid & 3) * 16;
      const f16* ksrc = qkv + (long)(b * SEQ + kt * 64 + row) * 1536 + 1024 + kvh * 64 + ds;
      union { uint4 u; f16 hh[8]; } a0, a1, b0, b1;
      a0.u = *(const uint4*)ksrc;
      a1.u = *(const uint4*)(ksrc + 8);
      b0.u = *(const uint4*)(ksrc + 256);
      b1.u = *(const uint4*)(ksrc + 264);
#pragma unroll
      for (int j = 0; j < 8; j++) {
        ks[row][ds + j] = (float)a0.hh[j];
        ks[row][ds + 8 + j] = (float)a1.hh[j];
        vs[row][ds + j] = (float)b0.hh[j];
        vs[row][ds + 8 + j] = (float)b1.hh[j];
      }
    }
    __syncthreads();
    float s0[8], s1[8];
#pragma unroll
    for (int jj = 0; jj < 8; jj++) { s0[jj] = 0.f; s1[jj] = 0.f; }
    for (int d4 = 0; d4 < 16; d4++) {
      float4 qa = *(const float4*)&qs[r0][d4 * 4];
      float4 qb = *(const float4*)&qs[r1][d4 * 4];
#pragma unroll
      for (int jj = 0; jj < 8; jj++) {
        float4 kk = *(const float4*)&ks[c * 8 + jj][d4 * 4];
        s0[jj] += qa.x * kk.x + qa.y * kk.y + qa.z * kk.z + qa.w * kk.w;
        s1[jj] += qb.x * kk.x + qb.y * kk.y + qb.z * kk.z + qb.w * kk.w;
      }
    }
    float mx0 = -1e30f, mx1 = -1e30f;
#pragma unroll
    for (int jj = 0; jj < 8; jj++) {
      int kg = kt * 64 + c * 8 + jj;
      s0[jj] = (kg <= q0 + r0) ? s0[jj] * 0.125f : -1e30f;
      s1[jj] = (kg <= q0 + r1) ? s1[jj] * 0.125f : -1e30f;
      mx0 = fmaxf(mx0, s0[jj]);
      mx1 = fmaxf(mx1, s1[jj]);
    }
    mx0 = fmaxf(mx0, __shfl_xor(mx0, 1));
    mx0 = fmaxf(mx0, __shfl_xor(mx0, 2));
    mx0 = fmaxf(mx0, __shfl_xor(mx0, 4));
    mx1 = fmaxf(mx1, __shfl_xor(mx1, 1));
    mx1 = fmaxf(mx1, __shfl_xor(mx1, 2));
    mx1 = fmaxf(mx1, __shfl_xor(mx1, 4));
    float mn0 = fmaxf(mr0, mx0), mn1 = fmaxf(mr1, mx1);
    float al0 = expf(mr0 - mn0), al1 = expf(mr1 - mn1);
    float sum0 = 0.f, sum1 = 0.f;
#pragma unroll
    for (int jj = 0; jj < 8; jj++) {
      s0[jj] = expf(s0[jj] - mn0);
      sum0 += s0[jj];
      s1[jj] = expf(s1[jj] - mn1);
      sum1 += s1[jj];
    }
    sum0 += __shfl_xor(sum0, 1); sum0 += __shfl_xor(sum0, 2); sum0 += __shfl_xor(sum0, 4);
    sum1 += __shfl_xor(sum1, 1); sum1 += __shfl_xor(sum1, 2); sum1 += __shfl_xor(sum1, 4);
    l0 = l0 * al0 + sum0;
    l1 = l1 * al1 + sum1;
#pragma unroll
    for (int d = 0; d < 8; d++) { o0[d] *= al0; o1[d] *= al1; }
    mr0 = mn0;
    mr1 = mn1;
    __syncthreads();  // everyone done reading ks before P overwrite
#pragma unroll
    for (int jj = 0; jj < 8; jj++) {
      ks[r0][c * 8 + jj] = s0[jj];
      ks[r1][c * 8 + jj] = s1[jj];
    }
    __syncthreads();
    for (int j = 0; j < 64; j++) {
      float pa = ks[r0][j], pb = ks[r1][j];
      float4 va = *(const float4*)&vs[j][c * 8];
      float4 vb = *(const float4*)&vs[j][c * 8 + 4];
      o0[0] += pa * va.x; o0[1] += pa * va.y; o0[2] += pa * va.z; o0[3] += pa * va.w;
      o0[4] += pa * vb.x; o0[5] += pa * vb.y; o0[6] += pa * vb.z; o0[7] += pa * vb.w;
      o1[0] += pb * va.x; o1[1] += pb * va.y; o1[2] += pb * va.z; o1[3] += pb * va.w;
      o1[4] += pb * vb.x; o1[5] += pb * vb.y; o1[6] += pb * vb.z; o1[7] += pb * vb.w;
    }
  }
  float iv0 = 1.0f / l0, iv1 = 1.0f / l1;
  f16* d0 = aout + (long)(b * SEQ + q0 + r0) * 1024 + h * 64 + c * 8;
  f16* d1 = aout + (long)(b * SEQ + q0 + r1) * 1024 + h * 64 + c * 8;
  union { f16 hh[4]; uint2 u; } w;
  w.hh[0] = (f16)(o0[0] * iv0); w.hh[1] = (f16)(o0[1] * iv0);
  w.hh[2] = (f16)(o0[2] * iv0); w.hh[3] = (f16)(o0[3] * iv0);
  *(uint2*)d0 = w.u;
  w.hh[0] = (f16)(o0[4] * iv0); w.hh[1] = (f16)(o0[5] * iv0);
  w.hh[2] = (f16)(o0[6] * iv0); w.hh[3] = (f16)(o0[7] * iv0);
  *(uint2*)(d0 + 4) = w.u;
  w.hh[0] = (f16)(o1[0] * iv1); w.hh[1] = (f16)(o1[1] * iv1);
  w.hh[2] = (f16)(o1[2] * iv1); w.hh[3] = (f16)(o1[3] * iv1);
  *(uint2*)d1 = w.u;
  w.hh[0] = (f16)(o1[4] * iv1); w.hh[1] = (f16)(o1[5] * iv1);
  w.hh[2] = (f16)(o1[6] * iv1); w.hh[3] = (f16)(o1[7] * iv1);
  *(uint2*)(d1 + 4) = w.u;
}

// ---------------------------------------------------------------------------
// router: full-f32 logits from resid (own RMS) -> softmax -> top2 + prob sums
// one wave per token; grid 512 x 256
// ---------------------------------------------------------------------------
__global__ __launch_bounds__(256) void router_kernel(
    const float* __restrict__ resid, const float* __restrict__ ln2w,
    const float* __restrict__ rw, int* __restrict__ topi, float* __restrict__ topw,
    float* __restrict__ psum) {
  int t = blockIdx.x * 4 + (threadIdx.x >> 6);
  int lane = threadIdx.x & 63;
  const float* x = resid + (long)t * 1024;
  float ss = 0.f;
  for (int h = lane; h < 1024; h += 64) {
    float v = x[h];
    ss += v * v;
  }
  ss = wave_sum64(ss);
  float sc = rsqrtf(ss * (1.0f / 1024.0f) + 1e-6f);
  float acc[8] = {0.f, 0.f, 0.f, 0.f, 0.f, 0.f, 0.f, 0.f};
  for (int h = lane; h < 1024; h += 64) {
    float xn = x[h] * sc * ln2w[h];
    const float4* r4 = (const float4*)(rw + h * 8);
    float4 ra = r4[0], rb = r4[1];
    acc[0] += xn * ra.x; acc[1] += xn * ra.y; acc[2] += xn * ra.z; acc[3] += xn * ra.w;
    acc[4] += xn * rb.x; acc[5] += xn * rb.y; acc[6] += xn * rb.z; acc[7] += xn * rb.w;
  }
#pragma unroll
  for (int m = 1; m < 64; m <<= 1) {
#pragma unroll
    for (int e = 0; e < 8; e++) acc[e] += __shfl_xor(acc[e], m);
  }
  if (lane == 0) {
    float mx = acc[0];
#pragma unroll
    for (int e = 1; e < 8; e++) mx = fmaxf(mx, acc[e]);
    float p[8];
    float s = 0.f;
#pragma unroll
    for (int e = 0; e < 8; e++) {
      p[e] = expf(acc[e] - mx);
      s += p[e];
    }
    float inv = 1.0f / s;
#pragma unroll
    for (int e = 0; e < 8; e++) {
      p[e] *= inv;
      atomicAdd(&psum[e], p[e]);
    }
    int i1 = 0;
    float b1 = p[0];
#pragma unroll
    for (int e = 1; e < 8; e++)
      if (p[e] > b1) { b1 = p[e]; i1 = e; }
    int i2 = -1;
    float b2 = -1.f;
#pragma unroll
    for (int e = 0; e < 8; e++)
      if (e != i1 && p[e] > b2) { b2 = p[e]; i2 = e; }
    topi[2 * t] = i1;
    topi[2 * t + 1] = i2;
    topw[2 * t] = b1;
    topw[2 * t + 1] = b2;
  }
}

// ---------------------------------------------------------------------------
// compact pairs by expert (single block) + aux output
// ---------------------------------------------------------------------------
__global__ __launch_bounds__(256) void compact_kernel(
    const int* __restrict__ topi, const float* __restrict__ topw, int* __restrict__ segc,
    int* __restrict__ sego, int* __restrict__ ptok, float* __restrict__ pw,
    int* __restrict__ tslot, const float* __restrict__ psum, float* __restrict__ aux_out) {
  __shared__ int c[8];
  __shared__ int off[9];
  __shared__ int cur[8];
  int tid = threadIdx.x;
  if (tid < 8) { c[tid] = 0; cur[tid] = 0; }
  __syncthreads();
  for (int i = tid; i < 4096; i += 256) atomicAdd(&c[topi[i]], 1);
  __syncthreads();
  if (tid == 0) {
    off[0] = 0;
    for (int e = 0; e < 8; e++) off[e + 1] = off[e] + c[e];
  }
  __syncthreads();
  for (int i = tid; i < 4096; i += 256) {
    int e = topi[i];
    int pidx = atomicAdd(&cur[e], 1);
    int slot = off[e] + pidx;
    ptok[slot] = i >> 1;
    pw[slot] = topw[i];
    tslot[i] = slot;
  }
  if (tid < 8) {
    segc[tid] = c[tid];
    sego[tid] = off[tid];
  }
  if (tid == 0) {
    float a = 0.f;
    for (int e = 0; e < 8; e++) {
      float d = psum[e] * (1.0f / 2048.0f) - 0.125f;
      a += d * d;
    }
    aux_out[0] = a * (1.0f / 8.0f);
  }
}

// ---------------------------------------------------------------------------
// silu(gate)*up on [rows, 2048] -> [rows, 1024]
// ---------------------------------------------------------------------------
__global__ __launch_bounds__(256) void silu_kernel(const f16* __restrict__ gu,
                                                   f16* __restrict__ act, int rows) {
  int id = blockIdx.x * 256 + threadIdx.x;
  int base = id * 4;
  int row = base >> 10;
  int i = base & 1023;
  if (row >= rows) return;
  union { uint2 u; f16 h[4]; } G, U, O;
  G.u = *(const uint2*)(gu + (long)row * 2048 + i);
  U.u = *(const uint2*)(gu + (long)row * 2048 + 1024 + i);
#pragma unroll
  for (int j = 0; j < 4; j++) {
    float g = (float)G.h[j];
    float u = (float)U.h[j];
    O.h[j] = (f16)(g / (1.0f + expf(-g)) * u);
  }
  *(uint2*)(act + (long)row * 1024 + i) = O.u;
}

// ---------------------------------------------------------------------------
// sgate = sigmoid(x2 . w); one wave per token
// ---------------------------------------------------------------------------
__global__ __launch_bounds__(256) void sgate_kernel(const f16* __restrict__ x2,
                                                    const float* __restrict__ gw,
                                                    float* __restrict__ sg) {
  int t = blockIdx.x * 4 + (threadIdx.x >> 6);
  int lane = threadIdx.x & 63;
  const f16* x = x2 + (long)t * 1024;
  float acc = 0.f;
  for (int h = lane; h < 1024; h += 64) acc += (float)x[h] * gw[h];
  acc = wave_sum64(acc);
  if (lane == 0) sg[t] = 1.0f / (1.0f + expf(-acc));
}

// ---------------------------------------------------------------------------
// final: out = resid + sgate*shared + y[slot0] + y[slot1]
// ---------------------------------------------------------------------------
__global__ __launch_bounds__(256) void final_kernel(
    const float* __restrict__ resid, const float* __restrict__ sh,
    const float* __restrict__ sg, const float* __restrict__ ybuf,
    const int* __restrict__ tslot, float* __restrict__ out) {
  int t = blockIdx.x;
  int tid = threadIdx.x;
  int s0 = tslot[2 * t], s1 = tslot[2 * t + 1];
  float g = sg[t];
  float4 a = ((const float4*)(resid + (long)t * 1024))[tid];
  float4 b = ((const float4*)(sh + (long)t * 1024))[tid];
  float4 c0 = ((const float4*)(ybuf + (long)s0 * 1024))[tid];
  float4 c1 = ((const float4*)(ybuf + (long)s1 * 1024))[tid];
  float4 o;
  o.x = a.x + g * b.x + c0.x + c1.x;
  o.y = a.y + g * b.y + c0.y + c1.y;
  o.z = a.z + g * b.z + c0.z + c1.z;
  o.w = a.w + g * b.w + c0.w + c1.w;
  ((float4*)(out + (long)t * 1024))[tid] = o;
}

// ---------------------------------------------------------------------------
extern "C" void kernel_launch(void* const* d_in, const int* in_sizes, int n_in,
                              void* d_out, int out_size, void* d_ws, size_t ws_size,
                              hipStream_t stream) {
  const float* hidden = (const float*)d_in[0];
  // d_in[1] attention_mask: exactly causal -1e9; applied analytically
  const int* pos_ids = (const int*)d_in[2];
  const float* ln1w = (const float*)d_in[3];
  const float* ln2w = (const float*)d_in[4];
  const float* wq = (const float*)d_in[5];
  const float* wk = (const float*)d_in[6];
  const float* wv = (const float*)d_in[7];
  const float* wo = (const float*)d_in[8];
  const float* router_w = (const float*)d_in[9];
  const float* egw = (const float*)d_in[10];
  const float* euw = (const float*)d_in[11];
  const float* edw = (const float*)d_in[12];
  const float* sgw = (const float*)d_in[13];
  const float* suw = (const float*)d_in[14];
  const float* sdw = (const float*)d_in[15];
  const float* segw = (const float*)d_in[16];
  float* out = (float*)d_out;

  char* p = (char*)d_ws;
  auto alloc = [&](size_t bytes) {
    char* r = p;
    p += (bytes + 255) & ~(size_t)255;
    return r;
  };
  f16* wqkvT = (f16*)alloc(1536l * 1024 * 2);
  f16* woT = (f16*)alloc(1024l * 1024 * 2);
  f16* sguT = (f16*)alloc(2048l * 1024 * 2);
  f16* sdT = (f16*)alloc(1024l * 1024 * 2);
  f16* guT = (f16*)alloc(8l * 2048 * 1024 * 2);
  f16* dnT = (f16*)alloc(8l * 1024 * 1024 * 2);
  f16* xln1 = (f16*)alloc(2048l * 1024 * 2);
  f16* qkv = (f16*)alloc(2048l * 1536 * 2);
  f16* attnO = (f16*)alloc(2048l * 1024 * 2);
  float* resid = (float*)alloc(2048l * 1024 * 4);
  f16* x2 = (f16*)alloc(2048l * 1024 * 2);
  f16* gs_us = (f16*)alloc(2048l * 2048 * 2);
  f16* act_s = (f16*)alloc(2048l * 1024 * 2);
  float* sh_out = (float*)alloc(2048l * 1024 * 4);
  f16* gu_r = (f16*)alloc(4096l * 2048 * 2);
  f16* act_r = (f16*)alloc(4096l * 1024 * 2);
  float* ybuf = (float*)alloc(4096l * 1024 * 4);
  float* sgate = (float*)alloc(2048 * 4);
  int* topi = (int*)alloc(4096 * 4);
  float* topw = (float*)alloc(4096 * 4);
  int* ptok = (int*)alloc(4096 * 4);
  float* pwts = (float*)alloc(4096 * 4);
  int* tslot = (int*)alloc(4096 * 4);
  int* segc = (int*)alloc(8 * 4);
  int* sego = (int*)alloc(8 * 4);
  float* psum = (float*)alloc(8 * 4);

  hipMemsetAsync(psum, 0, 8 * sizeof(float), stream);

  // weight transposes f32[K,N] -> f16[N,K]
  transpose_kernel<<<dim3(16, 16, 1), 256, 0, stream>>>(wq, wqkvT, 1024, 1024, 0, 0);
  transpose_kernel<<<dim3(4, 16, 1), 256, 0, stream>>>(wk, wqkvT + 1024l * 1024, 1024, 256, 0, 0);
  transpose_kernel<<<dim3(4, 16, 1), 256, 0, stream>>>(wv, wqkvT + 1280l * 1024, 1024, 256, 0, 0);
  transpose_kernel<<<dim3(16, 16, 1), 256, 0, stream>>>(wo, woT, 1024, 1024, 0, 0);
  transpose_kernel<<<dim3(16, 16, 1), 256, 0, stream>>>(sgw, sguT, 1024, 1024, 0, 0);
  transpose_kernel<<<dim3(16, 16, 1), 256, 0, stream>>>(suw, sguT + 1024l * 1024, 1024, 1024, 0, 0);
  transpose_kernel<<<dim3(16, 16, 1), 256, 0, stream>>>(sdw, sdT, 1024, 1024, 0, 0);
  transpose_kernel<<<dim3(16, 16, 8), 256, 0, stream>>>(egw, guT, 1024, 1024, 1024l * 1024, 2048l * 1024);
  transpose_kernel<<<dim3(16, 16, 8), 256, 0, stream>>>(euw, guT + 1024l * 1024, 1024, 1024, 1024l * 1024, 2048l * 1024);
  transpose_kernel<<<dim3(16, 16, 8), 256, 0, stream>>>(edw, dnT, 1024, 1024, 1024l * 1024, 1024l * 1024);

  // attention path
  rms_kernel<<<2048, 256, 0, stream>>>(hidden, ln1w, xln1);
  gemm_kernel<0><<<dim3(12, 16, 1), 256, 0, stream>>>(xln1, wqkvT, qkv, nullptr, nullptr, nullptr, nullptr, nullptr, 1536, 1024, 0);
  rope_kernel<<<5120, 256, 0, stream>>>(qkv, pos_ids);
  attn_kernel<<<dim3(32, 16, 1), 256, 0, stream>>>(qkv, attnO);
  gemm_kernel<1><<<dim3(8, 16, 1), 256, 0, stream>>>(attnO, woT, resid, hidden, nullptr, nullptr, nullptr, nullptr, 1024, 1024, 0);

  // MoE path
  rms_kernel<<<2048, 256, 0, stream>>>(resid, ln2w, x2);
  router_kernel<<<512, 256, 0, stream>>>(resid, ln2w, router_w, topi, topw, psum);
  compact_kernel<<<1, 256, 0, stream>>>(topi, topw, segc, sego, ptok, pwts, tslot, psum, out + 2097152);

  gemm_kernel<0><<<dim3(16, 16, 1), 256, 0, stream>>>(x2, sguT, gs_us, nullptr, nullptr, nullptr, nullptr, nullptr, 2048, 1024, 0);
  silu_kernel<<<2048, 256, 0, stream>>>(gs_us, act_s, 2048);
  gemm_kernel<2><<<dim3(8, 16, 1), 256, 0, stream>>>(act_s, sdT, sh_out, nullptr, nullptr, nullptr, nullptr, nullptr, 1024, 1024, 0);
  sgate_kernel<<<512, 256, 0, stream>>>(x2, segw, sgate);

  gemm_kernel<3><<<dim3(16, 32, 8), 256, 0, stream>>>(x2, guT, gu_r, nullptr, ptok, nullptr, segc, sego, 2048, 1024, 2048l * 1024);
  silu_kernel<<<4096, 256, 0, stream>>>(gu_r, act_r, 4096);
  gemm_kernel<4><<<dim3(8, 32, 8), 256, 0, stream>>>(act_r, dnT, ybuf, nullptr, nullptr, pwts, segc, sego, 1024, 1024, 1024l * 1024);

  final_kernel<<<2048, 256, 0, stream>>>(resid, sh_out, sgate, ybuf, tslot, out);
}

// Round 3
// 453.230 us; speedup vs baseline: 2.8135x; 1.7655x over previous
//
#include <hip/hip_runtime.h>
#include <cstdint>
#include <cstddef>

typedef _Float16 f16;
typedef _Float16 f16x8 __attribute__((ext_vector_type(8)));
typedef float f32x4 __attribute__((ext_vector_type(4)));

#define SEQ 1024

// ---------------------------------------------------------------------------
// helpers
// ---------------------------------------------------------------------------
__device__ __forceinline__ float wave_sum64(float v) {
#pragma unroll
  for (int m = 1; m < 64; m <<= 1) v += __shfl_xor(v, m);
  return v;
}

// ---------------------------------------------------------------------------
// transpose f32 [K,N] -> f16 [N,K]   (64x64 tiles via LDS)
// ---------------------------------------------------------------------------
__global__ __launch_bounds__(256) void transpose_kernel(
    const float* __restrict__ src, f16* __restrict__ dst,
    int K, int N, long src_z, long dst_z) {
  src += (long)blockIdx.z * src_z;
  dst += (long)blockIdx.z * dst_z;
  int n0 = blockIdx.x * 64, k0 = blockIdx.y * 64;
  __shared__ float tile[64][65];
  int tid = threadIdx.x;
  int rr = tid >> 4, cc = tid & 15;
#pragma unroll
  for (int i = 0; i < 4; i++) {
    int kr = i * 16 + rr;
    float4 v = *(const float4*)(src + (long)(k0 + kr) * N + n0 + cc * 4);
    tile[kr][cc * 4 + 0] = v.x;
    tile[kr][cc * 4 + 1] = v.y;
    tile[kr][cc * 4 + 2] = v.z;
    tile[kr][cc * 4 + 3] = v.w;
  }
  __syncthreads();
#pragma unroll
  for (int i = 0; i < 4; i++) {
    int nr = i * 16 + rr;
    union { f16 h[4]; uint2 u; } cv;
#pragma unroll
    for (int j = 0; j < 4; j++) cv.h[j] = (f16)tile[cc * 4 + j][nr];
    *(uint2*)(dst + (long)(n0 + nr) * K + k0 + cc * 4) = cv.u;
  }
}

// ---------------------------------------------------------------------------
// RMSNorm: f32 [T,1024] -> f16 [T,1024]
// ---------------------------------------------------------------------------
__global__ __launch_bounds__(256) void rms_kernel(const float* __restrict__ x,
                                                  const float* __restrict__ w,
                                                  f16* __restrict__ out) {
  long t = blockIdx.x;
  int tid = threadIdx.x;
  float4 v = ((const float4*)(x + t * 1024))[tid];
  float ss = v.x * v.x + v.y * v.y + v.z * v.z + v.w * v.w;
  ss = wave_sum64(ss);
  __shared__ float sred[4];
  if ((tid & 63) == 0) sred[tid >> 6] = ss;
  __syncthreads();
  float tot = sred[0] + sred[1] + sred[2] + sred[3];
  float sc = rsqrtf(tot * (1.0f / 1024.0f) + 1e-6f);
  float4 wv = ((const float4*)w)[tid];
  union { f16 h[4]; uint2 u; } cv;
  cv.h[0] = (f16)(v.x * wv.x * sc);
  cv.h[1] = (f16)(v.y * wv.y * sc);
  cv.h[2] = (f16)(v.z * wv.z * sc);
  cv.h[3] = (f16)(v.w * wv.w * sc);
  *(uint2*)(out + t * 1024 + tid * 4) = cv.u;
}

// ---------------------------------------------------------------------------
// GEMM: C[M,N] = A[M,K] * BT[N,K]^T   (f16 in, f32 acc via MFMA 16x16x32)
// 256 threads (4 waves), 128x128 tile, BK=64, global_load_lds(16B) staging
// with XOR-swizzled LDS placement.
// ---------------------------------------------------------------------------
template <int MODE>
__global__ __launch_bounds__(256) void gemm_kernel(
    const f16* __restrict__ A, const f16* __restrict__ BT, void* __restrict__ outp,
    const float* __restrict__ addsrc, const int* __restrict__ ptok,
    const float* __restrict__ pw, const int* __restrict__ segc,
    const int* __restrict__ sego, int N, int K, long bt_estride) {
  int n0 = blockIdx.x * 128;
  int m0 = blockIdx.y * 128;
  int cnt = 1 << 30, poff = 0;
  if (MODE >= 3) {
    int e = blockIdx.z;
    cnt = segc[e];
    poff = sego[e];
    if (cnt == 0 || m0 >= cnt) return;
    BT += (long)e * bt_estride;
  }
  __shared__ f16 smem[16384];
  f16* As = smem;
  f16* Bs = smem + 8192;
  int tid = threadIdx.x;
  int w = tid >> 6, lane = tid & 63;
  int quad = lane >> 4, l16 = lane & 15;
  int wm = (w >> 1) * 64, wn = (w & 1) * 64;

  const f16* agp[4];
  const f16* bgp[4];
#pragma unroll
  for (int i = 0; i < 4; i++) {
    int c = i * 256 + tid;
    int r = c >> 3;
    int kq = (c & 7) ^ (r & 7);
    int ar = m0 + r;
    if (MODE == 3) {
      int rr = ar < cnt ? ar : cnt - 1;
      agp[i] = A + (long)ptok[poff + rr] * K + kq * 8;
    } else if (MODE == 4) {
      int rr = ar < cnt ? ar : cnt - 1;
      agp[i] = A + (long)(poff + rr) * K + kq * 8;
    } else {
      agp[i] = A + (long)ar * K + kq * 8;
    }
    bgp[i] = BT + (long)(n0 + r) * K + kq * 8;
  }

  f32x4 acc[4][4] = {};

  for (int k0 = 0; k0 < K; k0 += 64) {
    __syncthreads();
#pragma unroll
    for (int i = 0; i < 4; i++) {
      __builtin_amdgcn_global_load_lds(
          (const __attribute__((address_space(1))) void*)(agp[i] + k0),
          (__attribute__((address_space(3))) void*)(As + (i * 256 + w * 64) * 8),
          16, 0, 0);
      __builtin_amdgcn_global_load_lds(
          (const __attribute__((address_space(1))) void*)(bgp[i] + k0),
          (__attribute__((address_space(3))) void*)(Bs + (i * 256 + w * 64) * 8),
          16, 0, 0);
    }
    __syncthreads();
#pragma unroll
    for (int kk = 0; kk < 2; kk++) {
      f16x8 af[4], bf[4];
      int q = kk * 4 + quad;
#pragma unroll
      for (int i = 0; i < 4; i++) {
        int ra = wm + i * 16 + l16;
        af[i] = *(const f16x8*)&As[ra * 64 + (q ^ (ra & 7)) * 8];
        int rb = wn + i * 16 + l16;
        bf[i] = *(const f16x8*)&Bs[rb * 64 + (q ^ (rb & 7)) * 8];
      }
#pragma unroll
      for (int i = 0; i < 4; i++)
#pragma unroll
        for (int j = 0; j < 4; j++)
          acc[i][j] = __builtin_amdgcn_mfma_f32_16x16x32_f16(af[i], bf[j], acc[i][j], 0, 0, 0);
    }
  }

  if (MODE == 1 || MODE == 2 || MODE == 4) {
#pragma unroll
    for (int i = 0; i < 4; i++) {
#pragma unroll
      for (int j = 0; j < 4; j++) {
        int col = n0 + wn + j * 16 + l16;
#pragma unroll
        for (int r = 0; r < 4; r++) {
          int row = m0 + wm + i * 16 + quad * 4 + r;
          float v = acc[i][j][r];
          if (MODE == 1) {
            ((float*)outp)[(long)row * N + col] = v + addsrc[(long)row * N + col];
          } else if (MODE == 2) {
            ((float*)outp)[(long)row * N + col] = v;
          } else {
            if (row < cnt) ((float*)outp)[(long)(poff + row) * N + col] = v * pw[poff + row];
          }
        }
      }
    }
  } else {
    __syncthreads();
#pragma unroll
    for (int i = 0; i < 4; i++)
#pragma unroll
      for (int j = 0; j < 4; j++)
#pragma unroll
        for (int r = 0; r < 4; r++) {
          int lr = wm + i * 16 + quad * 4 + r;
          int lc = wn + j * 16 + l16;
          smem[lr * 128 + lc] = (f16)acc[i][j][r];
        }
    __syncthreads();
#pragma unroll
    for (int ii = 0; ii < 8; ii++) {
      int c = ii * 256 + tid;
      int row = c >> 4, off = (c & 15) * 8;
      uint4 v = *(const uint4*)&smem[row * 128 + off];
      int grow = m0 + row;
      if (MODE == 0) {
        *(uint4*)&((f16*)outp)[(long)grow * N + n0 + off] = v;
      } else {
        if (grow < cnt) *(uint4*)&((f16*)outp)[(long)(poff + grow) * N + n0 + off] = v;
      }
    }
  }
}

// ---------------------------------------------------------------------------
// RoPE in-place on qkv f16 [T,1536]
// ---------------------------------------------------------------------------
__global__ __launch_bounds__(256) void rope_kernel(f16* __restrict__ qkv,
                                                   const int* __restrict__ pos_ids) {
  int idx = blockIdx.x * 256 + threadIdx.x;
  int i = idx & 31;
  int r2 = idx >> 5;
  int hh = r2 % 20;
  int t = r2 / 20;
  int pos = pos_ids[t];
  float f = (float)pos * expf((float)i * (-13.815510557964274f / 32.0f));
  float sv, cv;
  sincosf(f, &sv, &cv);
  int col = (hh < 16) ? (hh * 64 + i) : (1024 + (hh - 16) * 64 + i);
  f16* p = qkv + (long)t * 1536 + col;
  float x1 = (float)p[0], x2 = (float)p[32];
  p[0] = (f16)(x1 * cv - x2 * sv);
  p[32] = (f16)(x2 * cv + x1 * sv);
}

// ---------------------------------------------------------------------------
// V transpose: qkv v-section -> vT [B*NKV][64 d][1024 seq]
// grid (8, 16): (b*4+kvh, seq tile). Coalesced reads, 16B scattered writes.
// ---------------------------------------------------------------------------
__global__ __launch_bounds__(256) void vtrans_kernel(const f16* __restrict__ qkv,
                                                     f16* __restrict__ vT) {
  int bk = blockIdx.x;
  int st = blockIdx.y;
  int b = bk >> 2, kvh = bk & 3;
  int s0 = st * 64;
  int tid = threadIdx.x;
#pragma unroll
  for (int i = 0; i < 2; i++) {
    int c = i * 256 + tid;  // 512 = 64 d x 8 seq-chunks
    int d = c & 63, sc = c >> 6;
    union { uint4 u; f16 h[8]; } v;
#pragma unroll
    for (int j = 0; j < 8; j++)
      v.h[j] = qkv[(long)(b * SEQ + s0 + sc * 8 + j) * 1536 + 1280 + kvh * 64 + d];
    *(uint4*)&vT[((long)bk * 64 + d) * 1024 + s0 + sc * 8] = v.u;
  }
}

// ---------------------------------------------------------------------------
// MFMA flash attention. grid (B*NH=32, S/64=16), block 256 (4 waves).
// Each wave owns 16 Q rows. K/V tiles of 64 iterate with online softmax.
// Fragment layouts (HW-verified): A [m=l16][k=quad*8+j]; C/D row=quad*4+reg,
// col=l16. P round-trips per-wave LDS strip (XOR-swizzled, no barrier).
// ---------------------------------------------------------------------------
__global__ __launch_bounds__(256) void attn_kernel(const f16* __restrict__ qkv,
                                                   const f16* __restrict__ vT,
                                                   f16* __restrict__ aout) {
  int bh = blockIdx.x;
  int b = bh >> 4, h = bh & 15;
  int kvh = h >> 2;
  int qt = blockIdx.y;
  int q0 = qt * 64;
  int tid = threadIdx.x;
  int w = tid >> 6, lane = tid & 63;
  int quad = lane >> 4, l16 = lane & 15;

  __shared__ f16 smem[16384];  // Qs 4096 | Ks 4096 | Vs 4096 | Ps 4x1024
  f16* Qs = smem;
  f16* Ks = smem + 4096;
  f16* Vs = smem + 8192;
  f16* Psw = smem + 12288 + w * 1024;

  // stage Q once: row r cols h*64.., xor-swizzled source chunks
#pragma unroll
  for (int i = 0; i < 2; i++) {
    int c = i * 256 + tid;
    int r = c >> 3;
    int kq = (c & 7) ^ (r & 7);
    __builtin_amdgcn_global_load_lds(
        (const __attribute__((address_space(1))) void*)(qkv + (long)(b * SEQ + q0 + r) * 1536 + h * 64 + kq * 8),
        (__attribute__((address_space(3))) void*)(Qs + c * 8), 16, 0, 0);
  }

  float mr[4], lsum[4];
  f32x4 oacc[4] = {};
#pragma unroll
  for (int r = 0; r < 4; r++) { mr[r] = -1e30f; lsum[r] = 0.f; }

  for (int kt = 0; kt <= qt; kt++) {
    __syncthreads();  // prior iteration reads done
#pragma unroll
    for (int i = 0; i < 2; i++) {
      int c = i * 256 + tid;
      int r = c >> 3;
      int kq = (c & 7) ^ (r & 7);
      __builtin_amdgcn_global_load_lds(
          (const __attribute__((address_space(1))) void*)(qkv + (long)(b * SEQ + kt * 64 + r) * 1536 + 1024 + kvh * 64 + kq * 8),
          (__attribute__((address_space(3))) void*)(Ks + c * 8), 16, 0, 0);
      __builtin_amdgcn_global_load_lds(
          (const __attribute__((address_space(1))) void*)(vT + ((long)(b * 4 + kvh) * 64 + r) * 1024 + kt * 64 + kq * 8),
          (__attribute__((address_space(3))) void*)(Vs + c * 8), 16, 0, 0);
    }
    __syncthreads();  // staged data visible (also covers Q on kt==0)

    // S = Q . K^T for this wave's 16 q rows x 64 kv
    int m = w * 16 + l16;
    f16x8 aq0 = *(const f16x8*)&Qs[m * 64 + ((quad) ^ (m & 7)) * 8];
    f16x8 aq1 = *(const f16x8*)&Qs[m * 64 + ((4 + quad) ^ (m & 7)) * 8];
    f32x4 sacc[4];
#pragma unroll
    for (int j = 0; j < 4; j++) {
      int n = j * 16 + l16;
      f16x8 bk0 = *(const f16x8*)&Ks[n * 64 + ((quad) ^ (n & 7)) * 8];
      f16x8 bk1 = *(const f16x8*)&Ks[n * 64 + ((4 + quad) ^ (n & 7)) * 8];
      f32x4 z = {};
      z = __builtin_amdgcn_mfma_f32_16x16x32_f16(aq0, bk0, z, 0, 0, 0);
      z = __builtin_amdgcn_mfma_f32_16x16x32_f16(aq1, bk1, z, 0, 0, 0);
      sacc[j] = z;
    }

    bool diag = (kt == qt);
    float sv[4][4];
    float rowmax[4];
#pragma unroll
    for (int r = 0; r < 4; r++) rowmax[r] = -1e30f;
#pragma unroll
    for (int j = 0; j < 4; j++)
#pragma unroll
      for (int r = 0; r < 4; r++) {
        float s = sacc[j][r] * 0.125f;
        if (diag && (j * 16 + l16 > w * 16 + quad * 4 + r)) s = -1e30f;
        sv[j][r] = s;
        rowmax[r] = fmaxf(rowmax[r], s);
      }
#pragma unroll
    for (int r = 0; r < 4; r++) {
      rowmax[r] = fmaxf(rowmax[r], __shfl_xor(rowmax[r], 1));
      rowmax[r] = fmaxf(rowmax[r], __shfl_xor(rowmax[r], 2));
      rowmax[r] = fmaxf(rowmax[r], __shfl_xor(rowmax[r], 4));
      rowmax[r] = fmaxf(rowmax[r], __shfl_xor(rowmax[r], 8));
    }
#pragma unroll
    for (int r = 0; r < 4; r++) {
      float mn = fmaxf(mr[r], rowmax[r]);
      float al = __expf(mr[r] - mn);
      mr[r] = mn;
      float rs = 0.f;
#pragma unroll
      for (int j = 0; j < 4; j++) {
        float pv = __expf(sv[j][r] - mn);
        sv[j][r] = pv;
        rs += pv;
      }
      rs += __shfl_xor(rs, 1);
      rs += __shfl_xor(rs, 2);
      rs += __shfl_xor(rs, 4);
      rs += __shfl_xor(rs, 8);
      lsum[r] = lsum[r] * al + rs;
#pragma unroll
      for (int j = 0; j < 4; j++) oacc[j][r] *= al;
    }

    // write P to per-wave strip in A-layout (xor-swizzled), rows = q, cols = kv
#pragma unroll
    for (int j = 0; j < 4; j++)
#pragma unroll
      for (int r = 0; r < 4; r++) {
        int row = quad * 4 + r;
        int chunk = j * 2 + (l16 >> 3);
        Psw[row * 64 + (chunk ^ (row & 7)) * 8 + (l16 & 7)] = (f16)sv[j][r];
      }

    // O += P . V   (B-frag rows = d from Vs=vT tile)
    f16x8 pf0 = *(const f16x8*)&Psw[l16 * 64 + ((quad) ^ (l16 & 7)) * 8];
    f16x8 pf1 = *(const f16x8*)&Psw[l16 * 64 + ((4 + quad) ^ (l16 & 7)) * 8];
#pragma unroll
    for (int j = 0; j < 4; j++) {
      int n = j * 16 + l16;
      f16x8 v0 = *(const f16x8*)&Vs[n * 64 + ((quad) ^ (n & 7)) * 8];
      f16x8 v1 = *(const f16x8*)&Vs[n * 64 + ((4 + quad) ^ (n & 7)) * 8];
      oacc[j] = __builtin_amdgcn_mfma_f32_16x16x32_f16(pf0, v0, oacc[j], 0, 0, 0);
      oacc[j] = __builtin_amdgcn_mfma_f32_16x16x32_f16(pf1, v1, oacc[j], 0, 0, 0);
    }
  }

  // epilogue: O/l -> LDS [64 q][72] -> coalesced f16 stores
  __syncthreads();
  f16* Os = smem;
  float iv[4];
#pragma unroll
  for (int r = 0; r < 4; r++) iv[r] = 1.0f / lsum[r];
#pragma unroll
  for (int j = 0; j < 4; j++)
#pragma unroll
    for (int r = 0; r < 4; r++)
      Os[(w * 16 + quad * 4 + r) * 72 + j * 16 + l16] = (f16)(oacc[j][r] * iv[r]);
  __syncthreads();
#pragma unroll
  for (int i = 0; i < 2; i++) {
    int c = i * 256 + tid;
    int row = c >> 3, off = (c & 7) * 8;
    uint4 v = *(const uint4*)&Os[row * 72 + off];
    *(uint4*)&aout[(long)(b * SEQ + q0 + row) * 1024 + h * 64 + off] = v;
  }
}

// ---------------------------------------------------------------------------
// router: full-f32 logits from resid (own RMS) -> softmax -> top2 + probs out
// ---------------------------------------------------------------------------
__global__ __launch_bounds__(256) void router_kernel(
    const float* __restrict__ resid, const float* __restrict__ ln2w,
    const float* __restrict__ rw, int* __restrict__ topi, float* __restrict__ topw,
    float* __restrict__ probs) {
  int t = blockIdx.x * 4 + (threadIdx.x >> 6);
  int lane = threadIdx.x & 63;
  const float* x = resid + (long)t * 1024;
  float ss = 0.f;
  for (int h = lane; h < 1024; h += 64) {
    float v = x[h];
    ss += v * v;
  }
  ss = wave_sum64(ss);
  float sc = rsqrtf(ss * (1.0f / 1024.0f) + 1e-6f);
  float acc[8] = {0.f, 0.f, 0.f, 0.f, 0.f, 0.f, 0.f, 0.f};
  for (int h = lane; h < 1024; h += 64) {
    float xn = x[h] * sc * ln2w[h];
    const float4* r4 = (const float4*)(rw + h * 8);
    float4 ra = r4[0], rb = r4[1];
    acc[0] += xn * ra.x; acc[1] += xn * ra.y; acc[2] += xn * ra.z; acc[3] += xn * ra.w;
    acc[4] += xn * rb.x; acc[5] += xn * rb.y; acc[6] += xn * rb.z; acc[7] += xn * rb.w;
  }
#pragma unroll
  for (int m = 1; m < 64; m <<= 1) {
#pragma unroll
    for (int e = 0; e < 8; e++) acc[e] += __shfl_xor(acc[e], m);
  }
  if (lane == 0) {
    float mx = acc[0];
#pragma unroll
    for (int e = 1; e < 8; e++) mx = fmaxf(mx, acc[e]);
    float p[8];
    float s = 0.f;
#pragma unroll
    for (int e = 0; e < 8; e++) {
      p[e] = expf(acc[e] - mx);
      s += p[e];
    }
    float inv = 1.0f / s;
#pragma unroll
    for (int e = 0; e < 8; e++) p[e] *= inv;
    float4 pa = {p[0], p[1], p[2], p[3]};
    float4 pb = {p[4], p[5], p[6], p[7]};
    *(float4*)(probs + t * 8) = pa;
    *(float4*)(probs + t * 8 + 4) = pb;
    int i1 = 0;
    float b1 = p[0];
#pragma unroll
    for (int e = 1; e < 8; e++)
      if (p[e] > b1) { b1 = p[e]; i1 = e; }
    int i2 = -1;
    float b2 = -1.f;
#pragma unroll
    for (int e = 0; e < 8; e++)
      if (e != i1 && p[e] > b2) { b2 = p[e]; i2 = e; }
    topi[2 * t] = i1;
    topi[2 * t + 1] = i2;
    topw[2 * t] = b1;
    topw[2 * t + 1] = b2;
  }
}

// ---------------------------------------------------------------------------
// compact pairs by expert (single block) + psum reduction + aux output
// ---------------------------------------------------------------------------
__global__ __launch_bounds__(256) void compact_kernel(
    const int* __restrict__ topi, const float* __restrict__ topw, int* __restrict__ segc,
    int* __restrict__ sego, int* __restrict__ ptok, float* __restrict__ pw,
    int* __restrict__ tslot, const float* __restrict__ probs, float* __restrict__ aux_out) {
  __shared__ int c[8];
  __shared__ int off[9];
  __shared__ int cur[8];
  __shared__ float ps[4][8];
  int tid = threadIdx.x;
  if (tid < 8) { c[tid] = 0; cur[tid] = 0; }
  __syncthreads();
  for (int i = tid; i < 4096; i += 256) atomicAdd(&c[topi[i]], 1);

  float s8[8] = {0.f, 0.f, 0.f, 0.f, 0.f, 0.f, 0.f, 0.f};
  for (int i = tid; i < 2048; i += 256) {
    float4 a = *(const float4*)(probs + i * 8);
    float4 b = *(const float4*)(probs + i * 8 + 4);
    s8[0] += a.x; s8[1] += a.y; s8[2] += a.z; s8[3] += a.w;
    s8[4] += b.x; s8[5] += b.y; s8[6] += b.z; s8[7] += b.w;
  }
#pragma unroll
  for (int e = 0; e < 8; e++) s8[e] = wave_sum64(s8[e]);
  if ((tid & 63) == 0)
#pragma unroll
    for (int e = 0; e < 8; e++) ps[tid >> 6][e] = s8[e];
  __syncthreads();
  if (tid == 0) {
    off[0] = 0;
    for (int e = 0; e < 8; e++) off[e + 1] = off[e] + c[e];
    float a = 0.f;
    for (int e = 0; e < 8; e++) {
      float tot = ps[0][e] + ps[1][e] + ps[2][e] + ps[3][e];
      float d = tot * (1.0f / 2048.0f) - 0.125f;
      a += d * d;
    }
    aux_out[0] = a * (1.0f / 8.0f);
  }
  __syncthreads();
  for (int i = tid; i < 4096; i += 256) {
    int e = topi[i];
    int pidx = atomicAdd(&cur[e], 1);
    int slot = off[e] + pidx;
    ptok[slot] = i >> 1;
    pw[slot] = topw[i];
    tslot[i] = slot;
  }
  if (tid < 8) {
    segc[tid] = c[tid];
    sego[tid] = off[tid];
  }
}

// ---------------------------------------------------------------------------
// silu(gate)*up on [rows, 2048] -> [rows, 1024]
// ---------------------------------------------------------------------------
__global__ __launch_bounds__(256) void silu_kernel(const f16* __restrict__ gu,
                                                   f16* __restrict__ act, int rows) {
  int id = blockIdx.x * 256 + threadIdx.x;
  int base = id * 4;
  int row = base >> 10;
  int i = base & 1023;
  if (row >= rows) return;
  union { uint2 u; f16 h[4]; } G, U, O;
  G.u = *(const uint2*)(gu + (long)row * 2048 + i);
  U.u = *(const uint2*)(gu + (long)row * 2048 + 1024 + i);
#pragma unroll
  for (int j = 0; j < 4; j++) {
    float g = (float)G.h[j];
    float u = (float)U.h[j];
    O.h[j] = (f16)(g / (1.0f + expf(-g)) * u);
  }
  *(uint2*)(act + (long)row * 1024 + i) = O.u;
}

// ---------------------------------------------------------------------------
// sgate = sigmoid(x2 . w); one wave per token
// ---------------------------------------------------------------------------
__global__ __launch_bounds__(256) void sgate_kernel(const f16* __restrict__ x2,
                                                    const float* __restrict__ gw,
                                                    float* __restrict__ sg) {
  int t = blockIdx.x * 4 + (threadIdx.x >> 6);
  int lane = threadIdx.x & 63;
  const f16* x = x2 + (long)t * 1024;
  float acc = 0.f;
  for (int h = lane; h < 1024; h += 64) acc += (float)x[h] * gw[h];
  acc = wave_sum64(acc);
  if (lane == 0) sg[t] = 1.0f / (1.0f + expf(-acc));
}

// ---------------------------------------------------------------------------
// final: out = resid + sgate*shared + y[slot0] + y[slot1]
// ---------------------------------------------------------------------------
__global__ __launch_bounds__(256) void final_kernel(
    const float* __restrict__ resid, const float* __restrict__ sh,
    const float* __restrict__ sg, const float* __restrict__ ybuf,
    const int* __restrict__ tslot, float* __restrict__ out) {
  int t = blockIdx.x;
  int tid = threadIdx.x;
  int s0 = tslot[2 * t], s1 = tslot[2 * t + 1];
  float g = sg[t];
  float4 a = ((const float4*)(resid + (long)t * 1024))[tid];
  float4 b = ((const float4*)(sh + (long)t * 1024))[tid];
  float4 c0 = ((const float4*)(ybuf + (long)s0 * 1024))[tid];
  float4 c1 = ((const float4*)(ybuf + (long)s1 * 1024))[tid];
  float4 o;
  o.x = a.x + g * b.x + c0.x + c1.x;
  o.y = a.y + g * b.y + c0.y + c1.y;
  o.z = a.z + g * b.z + c0.z + c1.z;
  o.w = a.w + g * b.w + c0.w + c1.w;
  ((float4*)(out + (long)t * 1024))[tid] = o;
}

// ---------------------------------------------------------------------------
extern "C" void kernel_launch(void* const* d_in, const int* in_sizes, int n_in,
                              void* d_out, int out_size, void* d_ws, size_t ws_size,
                              hipStream_t stream) {
  const float* hidden = (const float*)d_in[0];
  const int* pos_ids = (const int*)d_in[2];
  const float* ln1w = (const float*)d_in[3];
  const float* ln2w = (const float*)d_in[4];
  const float* wq = (const float*)d_in[5];
  const float* wk = (const float*)d_in[6];
  const float* wv = (const float*)d_in[7];
  const float* wo = (const float*)d_in[8];
  const float* router_w = (const float*)d_in[9];
  const float* egw = (const float*)d_in[10];
  const float* euw = (const float*)d_in[11];
  const float* edw = (const float*)d_in[12];
  const float* sgw = (const float*)d_in[13];
  const float* suw = (const float*)d_in[14];
  const float* sdw = (const float*)d_in[15];
  const float* segw = (const float*)d_in[16];
  float* out = (float*)d_out;

  char* p = (char*)d_ws;
  auto alloc = [&](size_t bytes) {
    char* r = p;
    p += (bytes + 255) & ~(size_t)255;
    return r;
  };
  f16* wqkvT = (f16*)alloc(1536l * 1024 * 2);
  f16* woT = (f16*)alloc(1024l * 1024 * 2);
  f16* sguT = (f16*)alloc(2048l * 1024 * 2);
  f16* sdT = (f16*)alloc(1024l * 1024 * 2);
  f16* guT = (f16*)alloc(8l * 2048 * 1024 * 2);
  f16* dnT = (f16*)alloc(8l * 1024 * 1024 * 2);
  f16* xln1 = (f16*)alloc(2048l * 1024 * 2);
  f16* qkv = (f16*)alloc(2048l * 1536 * 2);
  f16* vT = (f16*)alloc(8l * 64 * 1024 * 2);
  f16* attnO = (f16*)alloc(2048l * 1024 * 2);
  float* resid = (float*)alloc(2048l * 1024 * 4);
  f16* x2 = (f16*)alloc(2048l * 1024 * 2);
  f16* gs_us = (f16*)alloc(2048l * 2048 * 2);
  f16* act_s = (f16*)alloc(2048l * 1024 * 2);
  float* sh_out = (float*)alloc(2048l * 1024 * 4);
  f16* gu_r = (f16*)alloc(4096l * 2048 * 2);
  f16* act_r = (f16*)alloc(4096l * 1024 * 2);
  float* ybuf = (float*)alloc(4096l * 1024 * 4);
  float* sgate = (float*)alloc(2048 * 4);
  int* topi = (int*)alloc(4096 * 4);
  float* topw = (float*)alloc(4096 * 4);
  float* probs = (float*)alloc(2048l * 8 * 4);
  int* ptok = (int*)alloc(4096 * 4);
  float* pwts = (float*)alloc(4096 * 4);
  int* tslot = (int*)alloc(4096 * 4);
  int* segc = (int*)alloc(8 * 4);
  int* sego = (int*)alloc(8 * 4);

  // weight transposes f32[K,N] -> f16[N,K]
  transpose_kernel<<<dim3(16, 16, 1), 256, 0, stream>>>(wq, wqkvT, 1024, 1024, 0, 0);
  transpose_kernel<<<dim3(4, 16, 1), 256, 0, stream>>>(wk, wqkvT + 1024l * 1024, 1024, 256, 0, 0);
  transpose_kernel<<<dim3(4, 16, 1), 256, 0, stream>>>(wv, wqkvT + 1280l * 1024, 1024, 256, 0, 0);
  transpose_kernel<<<dim3(16, 16, 1), 256, 0, stream>>>(wo, woT, 1024, 1024, 0, 0);
  transpose_kernel<<<dim3(16, 16, 1), 256, 0, stream>>>(sgw, sguT, 1024, 1024, 0, 0);
  transpose_kernel<<<dim3(16, 16, 1), 256, 0, stream>>>(suw, sguT + 1024l * 1024, 1024, 1024, 0, 0);
  transpose_kernel<<<dim3(16, 16, 1), 256, 0, stream>>>(sdw, sdT, 1024, 1024, 0, 0);
  transpose_kernel<<<dim3(16, 16, 8), 256, 0, stream>>>(egw, guT, 1024, 1024, 1024l * 1024, 2048l * 1024);
  transpose_kernel<<<dim3(16, 16, 8), 256, 0, stream>>>(euw, guT + 1024l * 1024, 1024, 1024, 1024l * 1024, 2048l * 1024);
  transpose_kernel<<<dim3(16, 16, 8), 256, 0, stream>>>(edw, dnT, 1024, 1024, 1024l * 1024, 1024l * 1024);

  // attention path
  rms_kernel<<<2048, 256, 0, stream>>>(hidden, ln1w, xln1);
  gemm_kernel<0><<<dim3(12, 16, 1), 256, 0, stream>>>(xln1, wqkvT, qkv, nullptr, nullptr, nullptr, nullptr, nullptr, 1536, 1024, 0);
  rope_kernel<<<5120, 256, 0, stream>>>(qkv, pos_ids);
  vtrans_kernel<<<dim3(8, 16, 1), 256, 0, stream>>>(qkv, vT);
  attn_kernel<<<dim3(32, 16, 1), 256, 0, stream>>>(qkv, vT, attnO);
  gemm_kernel<1><<<dim3(8, 16, 1), 256, 0, stream>>>(attnO, woT, resid, hidden, nullptr, nullptr, nullptr, nullptr, 1024, 1024, 0);

  // MoE path
  rms_kernel<<<2048, 256, 0, stream>>>(resid, ln2w, x2);
  router_kernel<<<512, 256, 0, stream>>>(resid, ln2w, router_w, topi, topw, probs);
  compact_kernel<<<1, 256, 0, stream>>>(topi, topw, segc, sego, ptok, pwts, tslot, probs, out + 2097152);

  gemm_kernel<0><<<dim3(16, 16, 1), 256, 0, stream>>>(x2, sguT, gs_us, nullptr, nullptr, nullptr, nullptr, nullptr, 2048, 1024, 0);
  silu_kernel<<<2048, 256, 0, stream>>>(gs_us, act_s, 2048);
  gemm_kernel<2><<<dim3(8, 16, 1), 256, 0, stream>>>(act_s, sdT, sh_out, nullptr, nullptr, nullptr, nullptr, nullptr, 1024, 1024, 0);
  sgate_kernel<<<512, 256, 0, stream>>>(x2, segw, sgate);

  gemm_kernel<3><<<dim3(16, 32, 8), 256, 0, stream>>>(x2, guT, gu_r, nullptr, ptok, nullptr, segc, sego, 2048, 1024, 2048l * 1024);
  silu_kernel<<<4096, 256, 0, stream>>>(gu_r, act_r, 4096);
  gemm_kernel<4><<<dim3(8, 32, 8), 256, 0, stream>>>(act_r, dnT, ybuf, nullptr, nullptr, pwts, segc, sego, 1024, 1024, 1024l * 1024);

  final_kernel<<<2048, 256, 0, stream>>>(resid, sh_out, sgate, ybuf, tslot, out);
}

// Round 4
// 414.078 us; speedup vs baseline: 3.0796x; 1.0946x over previous
//
#include <hip/hip_runtime.h>
#include <cstdint>
#include <cstddef>

typedef _Float16 f16;
typedef _Float16 f16x8 __attribute__((ext_vector_type(8)));
typedef float f32x4 __attribute__((ext_vector_type(4)));

#define SEQ 1024

// ---------------------------------------------------------------------------
// helpers
// ---------------------------------------------------------------------------
__device__ __forceinline__ float wave_sum64(float v) {
#pragma unroll
  for (int m = 1; m < 64; m <<= 1) v += __shfl_xor(v, m);
  return v;
}

// ---------------------------------------------------------------------------
// transpose f32 [K,N] -> f16 [N,K]   (64x64 tiles via LDS)
// ---------------------------------------------------------------------------
__global__ __launch_bounds__(256) void transpose_kernel(
    const float* __restrict__ src, f16* __restrict__ dst,
    int K, int N, long src_z, long dst_z) {
  src += (long)blockIdx.z * src_z;
  dst += (long)blockIdx.z * dst_z;
  int n0 = blockIdx.x * 64, k0 = blockIdx.y * 64;
  __shared__ float tile[64][65];
  int tid = threadIdx.x;
  int rr = tid >> 4, cc = tid & 15;
#pragma unroll
  for (int i = 0; i < 4; i++) {
    int kr = i * 16 + rr;
    float4 v = *(const float4*)(src + (long)(k0 + kr) * N + n0 + cc * 4);
    tile[kr][cc * 4 + 0] = v.x;
    tile[kr][cc * 4 + 1] = v.y;
    tile[kr][cc * 4 + 2] = v.z;
    tile[kr][cc * 4 + 3] = v.w;
  }
  __syncthreads();
#pragma unroll
  for (int i = 0; i < 4; i++) {
    int nr = i * 16 + rr;
    union { f16 h[4]; uint2 u; } cv;
#pragma unroll
    for (int j = 0; j < 4; j++) cv.h[j] = (f16)tile[cc * 4 + j][nr];
    *(uint2*)(dst + (long)(n0 + nr) * K + k0 + cc * 4) = cv.u;
  }
}

// ---------------------------------------------------------------------------
// RMSNorm: f32 [T,1024] -> f16 [T,1024]
// ---------------------------------------------------------------------------
__global__ __launch_bounds__(256) void rms_kernel(const float* __restrict__ x,
                                                  const float* __restrict__ w,
                                                  f16* __restrict__ out) {
  long t = blockIdx.x;
  int tid = threadIdx.x;
  float4 v = ((const float4*)(x + t * 1024))[tid];
  float ss = v.x * v.x + v.y * v.y + v.z * v.z + v.w * v.w;
  ss = wave_sum64(ss);
  __shared__ float sred[4];
  if ((tid & 63) == 0) sred[tid >> 6] = ss;
  __syncthreads();
  float tot = sred[0] + sred[1] + sred[2] + sred[3];
  float sc = rsqrtf(tot * (1.0f / 1024.0f) + 1e-6f);
  float4 wv = ((const float4*)w)[tid];
  union { f16 h[4]; uint2 u; } cv;
  cv.h[0] = (f16)(v.x * wv.x * sc);
  cv.h[1] = (f16)(v.y * wv.y * sc);
  cv.h[2] = (f16)(v.z * wv.z * sc);
  cv.h[3] = (f16)(v.w * wv.w * sc);
  *(uint2*)(out + t * 1024 + tid * 4) = cv.u;
}

// ---------------------------------------------------------------------------
// fused: resid = hidden + P1 + P2 (WO k-split partials); x2 = rms(resid)*w
// ---------------------------------------------------------------------------
__global__ __launch_bounds__(256) void rms2_kernel(
    const float* __restrict__ hidden, const float* __restrict__ p1,
    const float* __restrict__ p2, const float* __restrict__ w,
    float* __restrict__ resid, f16* __restrict__ out) {
  long t = blockIdx.x;
  int tid = threadIdx.x;
  float4 h = ((const float4*)(hidden + t * 1024))[tid];
  float4 a = ((const float4*)(p1 + t * 1024))[tid];
  float4 b = ((const float4*)(p2 + t * 1024))[tid];
  float4 v;
  v.x = h.x + a.x + b.x;
  v.y = h.y + a.y + b.y;
  v.z = h.z + a.z + b.z;
  v.w = h.w + a.w + b.w;
  ((float4*)(resid + t * 1024))[tid] = v;
  float ss = v.x * v.x + v.y * v.y + v.z * v.z + v.w * v.w;
  ss = wave_sum64(ss);
  __shared__ float sred[4];
  if ((tid & 63) == 0) sred[tid >> 6] = ss;
  __syncthreads();
  float tot = sred[0] + sred[1] + sred[2] + sred[3];
  float sc = rsqrtf(tot * (1.0f / 1024.0f) + 1e-6f);
  float4 wv = ((const float4*)w)[tid];
  union { f16 h[4]; uint2 u; } cv;
  cv.h[0] = (f16)(v.x * wv.x * sc);
  cv.h[1] = (f16)(v.y * wv.y * sc);
  cv.h[2] = (f16)(v.z * wv.z * sc);
  cv.h[3] = (f16)(v.w * wv.w * sc);
  *(uint2*)(out + t * 1024 + tid * 4) = cv.u;
}

// ---------------------------------------------------------------------------
// GEMM: C[M,N] = A[M,K] * BT[N,K]^T  (f16 in, f32 acc, MFMA 16x16x32)
// 256 threads (4 waves, 2x2), tile 128 x (32*TN), BK=64,
// global_load_lds(16B) staging with XOR-swizzled LDS placement.
// MODE 0: dense, f16 out (LDS-transposed coalesced stores)
// MODE 2: dense, f32 out, K-split via blockIdx.z (out += z*estride)
// MODE 3: moe segment (z), A rows via ptok, f16 out at poff+row
// MODE 4: moe segment (z), A rows direct at poff+row, f32 out scaled by pw
// ---------------------------------------------------------------------------
template <int MODE, int TN>
__global__ __launch_bounds__(256) void gemm_kernel(
    const f16* __restrict__ A, const f16* __restrict__ BT, void* __restrict__ outp,
    const int* __restrict__ ptok, const float* __restrict__ pw,
    const int* __restrict__ segc, const int* __restrict__ sego,
    int N, int K, long estride) {
  const int tile_n = 32 * TN;
  int n0 = blockIdx.x * tile_n;
  int m0 = blockIdx.y * 128;
  int cnt = 1 << 30, poff = 0;
  int kbeg = 0, klen = K;
  float* po = (float*)outp;
  if (MODE >= 3) {
    int e = blockIdx.z;
    cnt = segc[e];
    poff = sego[e];
    if (cnt == 0 || m0 >= cnt) return;
    BT += (long)e * estride;
  } else if (MODE == 2) {
    klen = K / gridDim.z;
    kbeg = blockIdx.z * klen;
    po += (long)blockIdx.z * estride;
  }
  __shared__ f16 smem[8192 + 2048 * TN];  // As 16KB | Bs 4KB*TN; epi reuses
  f16* As = smem;
  f16* Bs = smem + 8192;
  int tid = threadIdx.x;
  int w = tid >> 6, lane = tid & 63;
  int quad = lane >> 4, l16 = lane & 15;
  int wm = (w >> 1) * 64, wn = (w & 1) * (TN * 16);

  const f16* agp[4];
  const f16* bgp[TN];
#pragma unroll
  for (int i = 0; i < 4; i++) {
    int c = i * 256 + tid;
    int r = c >> 3;
    int kq = (c & 7) ^ (r & 7);
    int ar = m0 + r;
    if (MODE == 3) {
      int rr = ar < cnt ? ar : cnt - 1;
      agp[i] = A + (long)ptok[poff + rr] * K + kq * 8;
    } else if (MODE == 4) {
      int rr = ar < cnt ? ar : cnt - 1;
      agp[i] = A + (long)(poff + rr) * K + kq * 8;
    } else {
      agp[i] = A + (long)ar * K + kq * 8;
    }
  }
#pragma unroll
  for (int i = 0; i < TN; i++) {
    int c = i * 256 + tid;
    int r = c >> 3;
    int kq = (c & 7) ^ (r & 7);
    bgp[i] = BT + (long)(n0 + r) * K + kq * 8;
  }

  f32x4 acc[4][TN] = {};

  for (int k0 = kbeg; k0 < kbeg + klen; k0 += 64) {
    __syncthreads();
#pragma unroll
    for (int i = 0; i < 4; i++)
      __builtin_amdgcn_global_load_lds(
          (const __attribute__((address_space(1))) void*)(agp[i] + k0),
          (__attribute__((address_space(3))) void*)(As + (i * 256 + w * 64) * 8),
          16, 0, 0);
#pragma unroll
    for (int i = 0; i < TN; i++)
      __builtin_amdgcn_global_load_lds(
          (const __attribute__((address_space(1))) void*)(bgp[i] + k0),
          (__attribute__((address_space(3))) void*)(Bs + (i * 256 + w * 64) * 8),
          16, 0, 0);
    __syncthreads();
#pragma unroll
    for (int kk = 0; kk < 2; kk++) {
      f16x8 af[4], bf[TN];
      int q = kk * 4 + quad;
#pragma unroll
      for (int i = 0; i < 4; i++) {
        int ra = wm + i * 16 + l16;
        af[i] = *(const f16x8*)&As[ra * 64 + (q ^ (ra & 7)) * 8];
      }
#pragma unroll
      for (int j = 0; j < TN; j++) {
        int rb = wn + j * 16 + l16;
        bf[j] = *(const f16x8*)&Bs[rb * 64 + (q ^ (rb & 7)) * 8];
      }
#pragma unroll
      for (int i = 0; i < 4; i++)
#pragma unroll
        for (int j = 0; j < TN; j++)
          acc[i][j] = __builtin_amdgcn_mfma_f32_16x16x32_f16(af[i], bf[j], acc[i][j], 0, 0, 0);
    }
  }

  if (MODE == 2 || MODE == 4) {
#pragma unroll
    for (int i = 0; i < 4; i++) {
#pragma unroll
      for (int j = 0; j < TN; j++) {
        int col = n0 + wn + j * 16 + l16;
#pragma unroll
        for (int r = 0; r < 4; r++) {
          int row = m0 + wm + i * 16 + quad * 4 + r;
          float v = acc[i][j][r];
          if (MODE == 2) {
            po[(long)row * N + col] = v;
          } else {
            if (row < cnt) po[(long)(poff + row) * N + col] = v * pw[poff + row];
          }
        }
      }
    }
  } else {
    __syncthreads();
#pragma unroll
    for (int i = 0; i < 4; i++)
#pragma unroll
      for (int j = 0; j < TN; j++)
#pragma unroll
        for (int r = 0; r < 4; r++) {
          int lr = wm + i * 16 + quad * 4 + r;
          int lc = wn + j * 16 + l16;
          smem[lr * tile_n + lc] = (f16)acc[i][j][r];
        }
    __syncthreads();
    const int cpr = tile_n / 8;  // 16B chunks per row
#pragma unroll
    for (int ii = 0; ii < 2 * TN; ii++) {
      int c = ii * 256 + tid;
      int row = c / cpr, off = (c % cpr) * 8;
      uint4 v = *(const uint4*)&smem[row * tile_n + off];
      int grow = m0 + row;
      if (MODE == 0) {
        *(uint4*)&((f16*)outp)[(long)grow * N + n0 + off] = v;
      } else {
        if (grow < cnt) *(uint4*)&((f16*)outp)[(long)(poff + grow) * N + n0 + off] = v;
      }
    }
  }
}

// ---------------------------------------------------------------------------
// RoPE in-place on qkv f16 [T,1536]
// ---------------------------------------------------------------------------
__global__ __launch_bounds__(256) void rope_kernel(f16* __restrict__ qkv,
                                                   const int* __restrict__ pos_ids) {
  int idx = blockIdx.x * 256 + threadIdx.x;
  int i = idx & 31;
  int r2 = idx >> 5;
  int hh = r2 % 20;
  int t = r2 / 20;
  int pos = pos_ids[t];
  float f = (float)pos * expf((float)i * (-13.815510557964274f / 32.0f));
  float sv, cv;
  sincosf(f, &sv, &cv);
  int col = (hh < 16) ? (hh * 64 + i) : (1024 + (hh - 16) * 64 + i);
  f16* p = qkv + (long)t * 1536 + col;
  float x1 = (float)p[0], x2 = (float)p[32];
  p[0] = (f16)(x1 * cv - x2 * sv);
  p[32] = (f16)(x2 * cv + x1 * sv);
}

// ---------------------------------------------------------------------------
// V transpose: qkv v-section -> vT [B*NKV][64 d][1024 seq]
// ---------------------------------------------------------------------------
__global__ __launch_bounds__(256) void vtrans_kernel(const f16* __restrict__ qkv,
                                                     f16* __restrict__ vT) {
  int bk = blockIdx.x;
  int st = blockIdx.y;
  int b = bk >> 2, kvh = bk & 3;
  int s0 = st * 64;
  int tid = threadIdx.x;
#pragma unroll
  for (int i = 0; i < 2; i++) {
    int c = i * 256 + tid;
    int d = c & 63, sc = c >> 6;
    union { uint4 u; f16 h[8]; } v;
#pragma unroll
    for (int j = 0; j < 8; j++)
      v.h[j] = qkv[(long)(b * SEQ + s0 + sc * 8 + j) * 1536 + 1280 + kvh * 64 + d];
    *(uint4*)&vT[((long)bk * 64 + d) * 1024 + s0 + sc * 8] = v.u;
  }
}

// ---------------------------------------------------------------------------
// MFMA flash attention. grid (B*NH=32, S/64=16), block 256 (4 waves).
// ---------------------------------------------------------------------------
__global__ __launch_bounds__(256) void attn_kernel(const f16* __restrict__ qkv,
                                                   const f16* __restrict__ vT,
                                                   f16* __restrict__ aout) {
  int bh = blockIdx.x;
  int b = bh >> 4, h = bh & 15;
  int kvh = h >> 2;
  int qt = blockIdx.y;
  int q0 = qt * 64;
  int tid = threadIdx.x;
  int w = tid >> 6, lane = tid & 63;
  int quad = lane >> 4, l16 = lane & 15;

  __shared__ f16 smem[16384];  // Qs 4096 | Ks 4096 | Vs 4096 | Ps 4x1024
  f16* Qs = smem;
  f16* Ks = smem + 4096;
  f16* Vs = smem + 8192;
  f16* Psw = smem + 12288 + w * 1024;

#pragma unroll
  for (int i = 0; i < 2; i++) {
    int c = i * 256 + tid;
    int r = c >> 3;
    int kq = (c & 7) ^ (r & 7);
    __builtin_amdgcn_global_load_lds(
        (const __attribute__((address_space(1))) void*)(qkv + (long)(b * SEQ + q0 + r) * 1536 + h * 64 + kq * 8),
        (__attribute__((address_space(3))) void*)(Qs + c * 8), 16, 0, 0);
  }

  float mr[4], lsum[4];
  f32x4 oacc[4] = {};
#pragma unroll
  for (int r = 0; r < 4; r++) { mr[r] = -1e30f; lsum[r] = 0.f; }

  for (int kt = 0; kt <= qt; kt++) {
    __syncthreads();
#pragma unroll
    for (int i = 0; i < 2; i++) {
      int c = i * 256 + tid;
      int r = c >> 3;
      int kq = (c & 7) ^ (r & 7);
      __builtin_amdgcn_global_load_lds(
          (const __attribute__((address_space(1))) void*)(qkv + (long)(b * SEQ + kt * 64 + r) * 1536 + 1024 + kvh * 64 + kq * 8),
          (__attribute__((address_space(3))) void*)(Ks + c * 8), 16, 0, 0);
      __builtin_amdgcn_global_load_lds(
          (const __attribute__((address_space(1))) void*)(vT + ((long)(b * 4 + kvh) * 64 + r) * 1024 + kt * 64 + kq * 8),
          (__attribute__((address_space(3))) void*)(Vs + c * 8), 16, 0, 0);
    }
    __syncthreads();

    int m = w * 16 + l16;
    f16x8 aq0 = *(const f16x8*)&Qs[m * 64 + ((quad) ^ (m & 7)) * 8];
    f16x8 aq1 = *(const f16x8*)&Qs[m * 64 + ((4 + quad) ^ (m & 7)) * 8];
    f32x4 sacc[4];
#pragma unroll
    for (int j = 0; j < 4; j++) {
      int n = j * 16 + l16;
      f16x8 bk0 = *(const f16x8*)&Ks[n * 64 + ((quad) ^ (n & 7)) * 8];
      f16x8 bk1 = *(const f16x8*)&Ks[n * 64 + ((4 + quad) ^ (n & 7)) * 8];
      f32x4 z = {};
      z = __builtin_amdgcn_mfma_f32_16x16x32_f16(aq0, bk0, z, 0, 0, 0);
      z = __builtin_amdgcn_mfma_f32_16x16x32_f16(aq1, bk1, z, 0, 0, 0);
      sacc[j] = z;
    }

    bool diag = (kt == qt);
    float sv[4][4];
    float rowmax[4];
#pragma unroll
    for (int r = 0; r < 4; r++) rowmax[r] = -1e30f;
#pragma unroll
    for (int j = 0; j < 4; j++)
#pragma unroll
      for (int r = 0; r < 4; r++) {
        float s = sacc[j][r] * 0.125f;
        if (diag && (j * 16 + l16 > w * 16 + quad * 4 + r)) s = -1e30f;
        sv[j][r] = s;
        rowmax[r] = fmaxf(rowmax[r], s);
      }
#pragma unroll
    for (int r = 0; r < 4; r++) {
      rowmax[r] = fmaxf(rowmax[r], __shfl_xor(rowmax[r], 1));
      rowmax[r] = fmaxf(rowmax[r], __shfl_xor(rowmax[r], 2));
      rowmax[r] = fmaxf(rowmax[r], __shfl_xor(rowmax[r], 4));
      rowmax[r] = fmaxf(rowmax[r], __shfl_xor(rowmax[r], 8));
    }
#pragma unroll
    for (int r = 0; r < 4; r++) {
      float mn = fmaxf(mr[r], rowmax[r]);
      float al = __expf(mr[r] - mn);
      mr[r] = mn;
      float rs = 0.f;
#pragma unroll
      for (int j = 0; j < 4; j++) {
        float pv = __expf(sv[j][r] - mn);
        sv[j][r] = pv;
        rs += pv;
      }
      rs += __shfl_xor(rs, 1);
      rs += __shfl_xor(rs, 2);
      rs += __shfl_xor(rs, 4);
      rs += __shfl_xor(rs, 8);
      lsum[r] = lsum[r] * al + rs;
#pragma unroll
      for (int j = 0; j < 4; j++) oacc[j][r] *= al;
    }

#pragma unroll
    for (int j = 0; j < 4; j++)
#pragma unroll
      for (int r = 0; r < 4; r++) {
        int row = quad * 4 + r;
        int chunk = j * 2 + (l16 >> 3);
        Psw[row * 64 + (chunk ^ (row & 7)) * 8 + (l16 & 7)] = (f16)sv[j][r];
      }

    f16x8 pf0 = *(const f16x8*)&Psw[l16 * 64 + ((quad) ^ (l16 & 7)) * 8];
    f16x8 pf1 = *(const f16x8*)&Psw[l16 * 64 + ((4 + quad) ^ (l16 & 7)) * 8];
#pragma unroll
    for (int j = 0; j < 4; j++) {
      int n = j * 16 + l16;
      f16x8 v0 = *(const f16x8*)&Vs[n * 64 + ((quad) ^ (n & 7)) * 8];
      f16x8 v1 = *(const f16x8*)&Vs[n * 64 + ((4 + quad) ^ (n & 7)) * 8];
      oacc[j] = __builtin_amdgcn_mfma_f32_16x16x32_f16(pf0, v0, oacc[j], 0, 0, 0);
      oacc[j] = __builtin_amdgcn_mfma_f32_16x16x32_f16(pf1, v1, oacc[j], 0, 0, 0);
    }
  }

  __syncthreads();
  f16* Os = smem;
  float iv[4];
#pragma unroll
  for (int r = 0; r < 4; r++) iv[r] = 1.0f / lsum[r];
#pragma unroll
  for (int j = 0; j < 4; j++)
#pragma unroll
    for (int r = 0; r < 4; r++)
      Os[(w * 16 + quad * 4 + r) * 72 + j * 16 + l16] = (f16)(oacc[j][r] * iv[r]);
  __syncthreads();
#pragma unroll
  for (int i = 0; i < 2; i++) {
    int c = i * 256 + tid;
    int row = c >> 3, off = (c & 7) * 8;
    uint4 v = *(const uint4*)&Os[row * 72 + off];
    *(uint4*)&aout[(long)(b * SEQ + q0 + row) * 1024 + h * 64 + off] = v;
  }
}

// ---------------------------------------------------------------------------
// router: full-f32 logits from resid (own RMS) -> softmax -> top2 + probs out
// ---------------------------------------------------------------------------
__global__ __launch_bounds__(256) void router_kernel(
    const float* __restrict__ resid, const float* __restrict__ ln2w,
    const float* __restrict__ rw, int* __restrict__ topi, float* __restrict__ topw,
    float* __restrict__ probs) {
  int t = blockIdx.x * 4 + (threadIdx.x >> 6);
  int lane = threadIdx.x & 63;
  const float* x = resid + (long)t * 1024;
  float ss = 0.f;
  for (int h = lane; h < 1024; h += 64) {
    float v = x[h];
    ss += v * v;
  }
  ss = wave_sum64(ss);
  float sc = rsqrtf(ss * (1.0f / 1024.0f) + 1e-6f);
  float acc[8] = {0.f, 0.f, 0.f, 0.f, 0.f, 0.f, 0.f, 0.f};
  for (int h = lane; h < 1024; h += 64) {
    float xn = x[h] * sc * ln2w[h];
    const float4* r4 = (const float4*)(rw + h * 8);
    float4 ra = r4[0], rb = r4[1];
    acc[0] += xn * ra.x; acc[1] += xn * ra.y; acc[2] += xn * ra.z; acc[3] += xn * ra.w;
    acc[4] += xn * rb.x; acc[5] += xn * rb.y; acc[6] += xn * rb.z; acc[7] += xn * rb.w;
  }
#pragma unroll
  for (int m = 1; m < 64; m <<= 1) {
#pragma unroll
    for (int e = 0; e < 8; e++) acc[e] += __shfl_xor(acc[e], m);
  }
  if (lane == 0) {
    float mx = acc[0];
#pragma unroll
    for (int e = 1; e < 8; e++) mx = fmaxf(mx, acc[e]);
    float p[8];
    float s = 0.f;
#pragma unroll
    for (int e = 0; e < 8; e++) {
      p[e] = expf(acc[e] - mx);
      s += p[e];
    }
    float inv = 1.0f / s;
#pragma unroll
    for (int e = 0; e < 8; e++) p[e] *= inv;
    float4 pa = {p[0], p[1], p[2], p[3]};
    float4 pb = {p[4], p[5], p[6], p[7]};
    *(float4*)(probs + t * 8) = pa;
    *(float4*)(probs + t * 8 + 4) = pb;
    int i1 = 0;
    float b1 = p[0];
#pragma unroll
    for (int e = 1; e < 8; e++)
      if (p[e] > b1) { b1 = p[e]; i1 = e; }
    int i2 = -1;
    float b2 = -1.f;
#pragma unroll
    for (int e = 0; e < 8; e++)
      if (e != i1 && p[e] > b2) { b2 = p[e]; i2 = e; }
    topi[2 * t] = i1;
    topi[2 * t + 1] = i2;
    topw[2 * t] = b1;
    topw[2 * t + 1] = b2;
  }
}

// ---------------------------------------------------------------------------
// compact pairs by expert (single block) + psum reduction + aux output.
// Also fills segment 8 (shared expert): identity ptok rows 4096..6143, w=1.
// ---------------------------------------------------------------------------
__global__ __launch_bounds__(256) void compact_kernel(
    const int* __restrict__ topi, const float* __restrict__ topw, int* __restrict__ segc,
    int* __restrict__ sego, int* __restrict__ ptok, float* __restrict__ pw,
    int* __restrict__ tslot, const float* __restrict__ probs, float* __restrict__ aux_out) {
  __shared__ int c[8];
  __shared__ int off[9];
  __shared__ int cur[8];
  __shared__ float ps[4][8];
  int tid = threadIdx.x;
  if (tid < 8) { c[tid] = 0; cur[tid] = 0; }
  __syncthreads();
  for (int i = tid; i < 4096; i += 256) atomicAdd(&c[topi[i]], 1);
  for (int i = tid; i < 2048; i += 256) {
    ptok[4096 + i] = i;
    pw[4096 + i] = 1.0f;
  }

  float s8[8] = {0.f, 0.f, 0.f, 0.f, 0.f, 0.f, 0.f, 0.f};
  for (int i = tid; i < 2048; i += 256) {
    float4 a = *(const float4*)(probs + i * 8);
    float4 b = *(const float4*)(probs + i * 8 + 4);
    s8[0] += a.x; s8[1] += a.y; s8[2] += a.z; s8[3] += a.w;
    s8[4] += b.x; s8[5] += b.y; s8[6] += b.z; s8[7] += b.w;
  }
#pragma unroll
  for (int e = 0; e < 8; e++) s8[e] = wave_sum64(s8[e]);
  if ((tid & 63) == 0)
#pragma unroll
    for (int e = 0; e < 8; e++) ps[tid >> 6][e] = s8[e];
  __syncthreads();
  if (tid == 0) {
    off[0] = 0;
    for (int e = 0; e < 8; e++) off[e + 1] = off[e] + c[e];
    float a = 0.f;
    for (int e = 0; e < 8; e++) {
      float tot = ps[0][e] + ps[1][e] + ps[2][e] + ps[3][e];
      float d = tot * (1.0f / 2048.0f) - 0.125f;
      a += d * d;
    }
    aux_out[0] = a * (1.0f / 8.0f);
  }
  __syncthreads();
  for (int i = tid; i < 4096; i += 256) {
    int e = topi[i];
    int pidx = atomicAdd(&cur[e], 1);
    int slot = off[e] + pidx;
    ptok[slot] = i >> 1;
    pw[slot] = topw[i];
    tslot[i] = slot;
  }
  if (tid < 8) {
    segc[tid] = c[tid];
    sego[tid] = off[tid];
  }
  if (tid == 0) {
    segc[8] = 2048;
    sego[8] = 4096;
  }
}

// ---------------------------------------------------------------------------
// silu(gate)*up on [rows, 2048] -> [rows, 1024]
// ---------------------------------------------------------------------------
__global__ __launch_bounds__(256) void silu_kernel(const f16* __restrict__ gu,
                                                   f16* __restrict__ act, int rows) {
  int id = blockIdx.x * 256 + threadIdx.x;
  int base = id * 4;
  int row = base >> 10;
  int i = base & 1023;
  if (row >= rows) return;
  union { uint2 u; f16 h[4]; } G, U, O;
  G.u = *(const uint2*)(gu + (long)row * 2048 + i);
  U.u = *(const uint2*)(gu + (long)row * 2048 + 1024 + i);
#pragma unroll
  for (int j = 0; j < 4; j++) {
    float g = (float)G.h[j];
    float u = (float)U.h[j];
    O.h[j] = (f16)(g / (1.0f + expf(-g)) * u);
  }
  *(uint2*)(act + (long)row * 1024 + i) = O.u;
}

// ---------------------------------------------------------------------------
// sgate = sigmoid(x2 . w); one wave per token
// ---------------------------------------------------------------------------
__global__ __launch_bounds__(256) void sgate_kernel(const f16* __restrict__ x2,
                                                    const float* __restrict__ gw,
                                                    float* __restrict__ sg) {
  int t = blockIdx.x * 4 + (threadIdx.x >> 6);
  int lane = threadIdx.x & 63;
  const f16* x = x2 + (long)t * 1024;
  float acc = 0.f;
  for (int h = lane; h < 1024; h += 64) acc += (float)x[h] * gw[h];
  acc = wave_sum64(acc);
  if (lane == 0) sg[t] = 1.0f / (1.0f + expf(-acc));
}

// ---------------------------------------------------------------------------
// final: out = resid + sgate*y[4096+t] + y[slot0] + y[slot1]
// ---------------------------------------------------------------------------
__global__ __launch_bounds__(256) void final_kernel(
    const float* __restrict__ resid, const float* __restrict__ sg,
    const float* __restrict__ ybuf, const int* __restrict__ tslot,
    float* __restrict__ out) {
  int t = blockIdx.x;
  int tid = threadIdx.x;
  int s0 = tslot[2 * t], s1 = tslot[2 * t + 1];
  float g = sg[t];
  float4 a = ((const float4*)(resid + (long)t * 1024))[tid];
  float4 b = ((const float4*)(ybuf + (long)(4096 + t) * 1024))[tid];
  float4 c0 = ((const float4*)(ybuf + (long)s0 * 1024))[tid];
  float4 c1 = ((const float4*)(ybuf + (long)s1 * 1024))[tid];
  float4 o;
  o.x = a.x + g * b.x + c0.x + c1.x;
  o.y = a.y + g * b.y + c0.y + c1.y;
  o.z = a.z + g * b.z + c0.z + c1.z;
  o.w = a.w + g * b.w + c0.w + c1.w;
  ((float4*)(out + (long)t * 1024))[tid] = o;
}

// ---------------------------------------------------------------------------
extern "C" void kernel_launch(void* const* d_in, const int* in_sizes, int n_in,
                              void* d_out, int out_size, void* d_ws, size_t ws_size,
                              hipStream_t stream) {
  const float* hidden = (const float*)d_in[0];
  const int* pos_ids = (const int*)d_in[2];
  const float* ln1w = (const float*)d_in[3];
  const float* ln2w = (const float*)d_in[4];
  const float* wq = (const float*)d_in[5];
  const float* wk = (const float*)d_in[6];
  const float* wv = (const float*)d_in[7];
  const float* wo = (const float*)d_in[8];
  const float* router_w = (const float*)d_in[9];
  const float* egw = (const float*)d_in[10];
  const float* euw = (const float*)d_in[11];
  const float* edw = (const float*)d_in[12];
  const float* sgw = (const float*)d_in[13];
  const float* suw = (const float*)d_in[14];
  const float* sdw = (const float*)d_in[15];
  const float* segw = (const float*)d_in[16];
  float* out = (float*)d_out;

  char* p = (char*)d_ws;
  auto alloc = [&](size_t bytes) {
    char* r = p;
    p += (bytes + 255) & ~(size_t)255;
    return r;
  };
  f16* wqkvT = (f16*)alloc(1536l * 1024 * 2);
  f16* woT = (f16*)alloc(1024l * 1024 * 2);
  f16* guT = (f16*)alloc(9l * 2048 * 1024 * 2);   // experts 0-7 + shared(8)
  f16* dnT = (f16*)alloc(9l * 1024 * 1024 * 2);
  f16* xln1 = (f16*)alloc(2048l * 1024 * 2);
  f16* qkv = (f16*)alloc(2048l * 1536 * 2);
  f16* vT = (f16*)alloc(8l * 64 * 1024 * 2);
  f16* attnO = (f16*)alloc(2048l * 1024 * 2);
  float* resid = (float*)alloc(2048l * 1024 * 4);
  f16* x2 = (f16*)alloc(2048l * 1024 * 2);
  f16* gu_all = (f16*)alloc(6144l * 2048 * 2);    // also aliases wo_part
  f16* act_all = (f16*)alloc(6144l * 1024 * 2);
  float* ybuf = (float*)alloc(6144l * 1024 * 4);
  float* sgate = (float*)alloc(2048 * 4);
  int* topi = (int*)alloc(4096 * 4);
  float* topw = (float*)alloc(4096 * 4);
  float* probs = (float*)alloc(2048l * 8 * 4);
  int* ptok = (int*)alloc(6144 * 4);
  float* pwts = (float*)alloc(6144 * 4);
  int* tslot = (int*)alloc(4096 * 4);
  int* segc = (int*)alloc(9 * 4);
  int* sego = (int*)alloc(9 * 4);
  // WO k-split partials alias gu_all (lifetimes disjoint: partials consumed
  // by rms2 before the g/u GEMM writes gu_all)
  float* wo_part = (float*)gu_all;  // 2 x [2048*1024] f32 = 16.8 MB < 25 MB

  // weight transposes f32[K,N] -> f16[N,K]
  transpose_kernel<<<dim3(16, 16, 1), 256, 0, stream>>>(wq, wqkvT, 1024, 1024, 0, 0);
  transpose_kernel<<<dim3(4, 16, 1), 256, 0, stream>>>(wk, wqkvT + 1024l * 1024, 1024, 256, 0, 0);
  transpose_kernel<<<dim3(4, 16, 1), 256, 0, stream>>>(wv, wqkvT + 1280l * 1024, 1024, 256, 0, 0);
  transpose_kernel<<<dim3(16, 16, 1), 256, 0, stream>>>(wo, woT, 1024, 1024, 0, 0);
  transpose_kernel<<<dim3(16, 16, 8), 256, 0, stream>>>(egw, guT, 1024, 1024, 1024l * 1024, 2048l * 1024);
  transpose_kernel<<<dim3(16, 16, 8), 256, 0, stream>>>(euw, guT + 1024l * 1024, 1024, 1024, 1024l * 1024, 2048l * 1024);
  transpose_kernel<<<dim3(16, 16, 1), 256, 0, stream>>>(sgw, guT + 8l * 2048 * 1024, 1024, 1024, 0, 0);
  transpose_kernel<<<dim3(16, 16, 1), 256, 0, stream>>>(suw, guT + 8l * 2048 * 1024 + 1024l * 1024, 1024, 1024, 0, 0);
  transpose_kernel<<<dim3(16, 16, 8), 256, 0, stream>>>(edw, dnT, 1024, 1024, 1024l * 1024, 1024l * 1024);
  transpose_kernel<<<dim3(16, 16, 1), 256, 0, stream>>>(sdw, dnT + 8l * 1024 * 1024, 1024, 1024, 0, 0);

  // attention path
  rms_kernel<<<2048, 256, 0, stream>>>(hidden, ln1w, xln1);
  gemm_kernel<0, 2><<<dim3(24, 16, 1), 256, 0, stream>>>(xln1, wqkvT, qkv, nullptr, nullptr, nullptr, nullptr, 1536, 1024, 0);
  rope_kernel<<<5120, 256, 0, stream>>>(qkv, pos_ids);
  vtrans_kernel<<<dim3(8, 16, 1), 256, 0, stream>>>(qkv, vT);
  attn_kernel<<<dim3(32, 16, 1), 256, 0, stream>>>(qkv, vT, attnO);
  // WO: K-split x2 into f32 partials
  gemm_kernel<2, 2><<<dim3(16, 16, 2), 256, 0, stream>>>(attnO, woT, wo_part, nullptr, nullptr, nullptr, nullptr, 1024, 1024, 2048l * 1024);
  rms2_kernel<<<2048, 256, 0, stream>>>(hidden, wo_part, wo_part + 2048l * 1024, ln2w, resid, x2);

  // MoE path (shared expert folded in as segment 8)
  router_kernel<<<512, 256, 0, stream>>>(resid, ln2w, router_w, topi, topw, probs);
  compact_kernel<<<1, 256, 0, stream>>>(topi, topw, segc, sego, ptok, pwts, tslot, probs, out + 2097152);
  sgate_kernel<<<512, 256, 0, stream>>>(x2, segw, sgate);

  gemm_kernel<3, 4><<<dim3(16, 16, 9), 256, 0, stream>>>(x2, guT, gu_all, ptok, pwts, segc, sego, 2048, 1024, 2048l * 1024);
  silu_kernel<<<6144, 256, 0, stream>>>(gu_all, act_all, 6144);
  gemm_kernel<4, 2><<<dim3(16, 16, 9), 256, 0, stream>>>(act_all, dnT, ybuf, ptok, pwts, segc, sego, 1024, 1024, 1024l * 1024);

  final_kernel<<<2048, 256, 0, stream>>>(resid, sgate, ybuf, tslot, out);
}

// Round 5
// 402.705 us; speedup vs baseline: 3.1665x; 1.0282x over previous
//
#include <hip/hip_runtime.h>
#include <cstdint>
#include <cstddef>

typedef _Float16 f16;
typedef _Float16 f16x8 __attribute__((ext_vector_type(8)));
typedef float f32x4 __attribute__((ext_vector_type(4)));

#define SEQ 1024

// ---------------------------------------------------------------------------
// helpers
// ---------------------------------------------------------------------------
__device__ __forceinline__ float wave_sum64(float v) {
#pragma unroll
  for (int m = 1; m < 64; m <<= 1) v += __shfl_xor(v, m);
  return v;
}

// ---------------------------------------------------------------------------
// transpose f32 [K,N] -> f16 [N,K]   (64x64 tiles via LDS)
// ---------------------------------------------------------------------------
__global__ __launch_bounds__(256) void transpose_kernel(
    const float* __restrict__ src, f16* __restrict__ dst,
    int K, int N, long src_z, long dst_z) {
  src += (long)blockIdx.z * src_z;
  dst += (long)blockIdx.z * dst_z;
  int n0 = blockIdx.x * 64, k0 = blockIdx.y * 64;
  __shared__ float tile[64][65];
  int tid = threadIdx.x;
  int rr = tid >> 4, cc = tid & 15;
#pragma unroll
  for (int i = 0; i < 4; i++) {
    int kr = i * 16 + rr;
    float4 v = *(const float4*)(src + (long)(k0 + kr) * N + n0 + cc * 4);
    tile[kr][cc * 4 + 0] = v.x;
    tile[kr][cc * 4 + 1] = v.y;
    tile[kr][cc * 4 + 2] = v.z;
    tile[kr][cc * 4 + 3] = v.w;
  }
  __syncthreads();
#pragma unroll
  for (int i = 0; i < 4; i++) {
    int nr = i * 16 + rr;
    union { f16 h[4]; uint2 u; } cv;
#pragma unroll
    for (int j = 0; j < 4; j++) cv.h[j] = (f16)tile[cc * 4 + j][nr];
    *(uint2*)(dst + (long)(n0 + nr) * K + k0 + cc * 4) = cv.u;
  }
}

// ---------------------------------------------------------------------------
// RMSNorm: f32 [T,1024] -> f16 [T,1024]
// ---------------------------------------------------------------------------
__global__ __launch_bounds__(256) void rms_kernel(const float* __restrict__ x,
                                                  const float* __restrict__ w,
                                                  f16* __restrict__ out) {
  long t = blockIdx.x;
  int tid = threadIdx.x;
  float4 v = ((const float4*)(x + t * 1024))[tid];
  float ss = v.x * v.x + v.y * v.y + v.z * v.z + v.w * v.w;
  ss = wave_sum64(ss);
  __shared__ float sred[4];
  if ((tid & 63) == 0) sred[tid >> 6] = ss;
  __syncthreads();
  float tot = sred[0] + sred[1] + sred[2] + sred[3];
  float sc = rsqrtf(tot * (1.0f / 1024.0f) + 1e-6f);
  float4 wv = ((const float4*)w)[tid];
  union { f16 h[4]; uint2 u; } cv;
  cv.h[0] = (f16)(v.x * wv.x * sc);
  cv.h[1] = (f16)(v.y * wv.y * sc);
  cv.h[2] = (f16)(v.z * wv.z * sc);
  cv.h[3] = (f16)(v.w * wv.w * sc);
  *(uint2*)(out + t * 1024 + tid * 4) = cv.u;
}

// ---------------------------------------------------------------------------
// fused: resid = hidden + P1 + P2 (WO k-split partials) written to OUT (f32);
// x2 = rms(resid)*w.  MoE down-GEMM later atomicAdds into OUT.
// ---------------------------------------------------------------------------
__global__ __launch_bounds__(256) void rms2_kernel(
    const float* __restrict__ hidden, const float* __restrict__ p1,
    const float* __restrict__ p2, const float* __restrict__ w,
    float* __restrict__ out_resid, f16* __restrict__ out) {
  long t = blockIdx.x;
  int tid = threadIdx.x;
  float4 h = ((const float4*)(hidden + t * 1024))[tid];
  float4 a = ((const float4*)(p1 + t * 1024))[tid];
  float4 b = ((const float4*)(p2 + t * 1024))[tid];
  float4 v;
  v.x = h.x + a.x + b.x;
  v.y = h.y + a.y + b.y;
  v.z = h.z + a.z + b.z;
  v.w = h.w + a.w + b.w;
  ((float4*)(out_resid + t * 1024))[tid] = v;
  float ss = v.x * v.x + v.y * v.y + v.z * v.z + v.w * v.w;
  ss = wave_sum64(ss);
  __shared__ float sred[4];
  if ((tid & 63) == 0) sred[tid >> 6] = ss;
  __syncthreads();
  float tot = sred[0] + sred[1] + sred[2] + sred[3];
  float sc = rsqrtf(tot * (1.0f / 1024.0f) + 1e-6f);
  float4 wv = ((const float4*)w)[tid];
  union { f16 h[4]; uint2 u; } cv;
  cv.h[0] = (f16)(v.x * wv.x * sc);
  cv.h[1] = (f16)(v.y * wv.y * sc);
  cv.h[2] = (f16)(v.z * wv.z * sc);
  cv.h[3] = (f16)(v.w * wv.w * sc);
  *(uint2*)(out + t * 1024 + tid * 4) = cv.u;
}

// ---------------------------------------------------------------------------
// GEMM: C[M,N] = A[M,K] * BT[N,K]^T  (f16 in, f32 acc, MFMA 16x16x32)
// 256 threads (4 waves, 2x2), tile 128 x (32*TN), BK=64,
// global_load_lds(16B) staging with XOR-swizzled LDS placement.
// MODE 0: dense, f16 out via LDS transpose; ROPE=1 applies rotary to
//         cols < 1280 (q/k heads, 64-col head-aligned tiles) during store.
// MODE 2: dense, f32 out, K-split via blockIdx.z (out += z*estride)
// MODE 5: moe segment (z): A rows via ptok; B-tile = 64 gate + 64 up rows of
//         guT; epilogue act = silu(g)*u, f16 out rows poff+row (TN must be 4)
// MODE 6: moe segment (z): A rows direct at poff+row; epilogue atomicAdd of
//         acc * pw[poff+row] into out[ptok[poff+row]*N + col]  (f32)
// ---------------------------------------------------------------------------
template <int MODE, int TN, int ROPE>
__global__ __launch_bounds__(256) void gemm_kernel(
    const f16* __restrict__ A, const f16* __restrict__ BT, void* __restrict__ outp,
    const int* __restrict__ ptok, const float* __restrict__ pw,
    const int* __restrict__ segc, const int* __restrict__ sego,
    const int* __restrict__ pos_ids, int N, int K, long estride) {
  const int tile_n = 32 * TN;
  int n0 = blockIdx.x * tile_n;
  int a0 = blockIdx.x * 64;  // MODE5 act-col base
  int m0 = blockIdx.y * 128;
  int cnt = 1 << 30, poff = 0;
  int kbeg = 0, klen = K;
  float* po = (float*)outp;
  if (MODE >= 5) {
    int e = blockIdx.z;
    cnt = segc[e];
    poff = sego[e];
    if (cnt == 0 || m0 >= cnt) return;
    BT += (long)e * estride;
  } else if (MODE == 2) {
    klen = K / gridDim.z;
    kbeg = blockIdx.z * klen;
    po += (long)blockIdx.z * estride;
  }
  constexpr int STAGE = 8192 + 2048 * TN;
  constexpr int EPI = (MODE == 0 || MODE == 5) ? 128 * (32 * TN + 8) : 0;
  constexpr int SMEMN = STAGE > EPI ? STAGE : EPI;
  __shared__ f16 smem[SMEMN];
  f16* As = smem;
  f16* Bs = smem + 8192;
  int tid = threadIdx.x;
  int w = tid >> 6, lane = tid & 63;
  int quad = lane >> 4, l16 = lane & 15;
  int wm = (w >> 1) * 64, wn = (w & 1) * (TN * 16);

  const f16* agp[4];
  const f16* bgp[TN];
#pragma unroll
  for (int i = 0; i < 4; i++) {
    int c = i * 256 + tid;
    int r = c >> 3;
    int kq = (c & 7) ^ (r & 7);
    int ar = m0 + r;
    if (MODE == 5) {
      int rr = ar < cnt ? ar : cnt - 1;
      agp[i] = A + (long)ptok[poff + rr] * K + kq * 8;
    } else if (MODE == 6) {
      int rr = ar < cnt ? ar : cnt - 1;
      agp[i] = A + (long)(poff + rr) * K + kq * 8;
    } else {
      agp[i] = A + (long)ar * K + kq * 8;
    }
  }
#pragma unroll
  for (int i = 0; i < TN; i++) {
    int c = i * 256 + tid;
    int r = c >> 3;
    int kq = (c & 7) ^ (r & 7);
    long br;
    if (MODE == 5) br = (r < 64) ? (a0 + r) : (1024 + a0 + (r - 64));
    else br = n0 + r;
    bgp[i] = BT + br * K + kq * 8;
  }

  f32x4 acc[4][TN] = {};

  for (int k0 = kbeg; k0 < kbeg + klen; k0 += 64) {
    __syncthreads();
#pragma unroll
    for (int i = 0; i < 4; i++)
      __builtin_amdgcn_global_load_lds(
          (const __attribute__((address_space(1))) void*)(agp[i] + k0),
          (__attribute__((address_space(3))) void*)(As + (i * 256 + w * 64) * 8),
          16, 0, 0);
#pragma unroll
    for (int i = 0; i < TN; i++)
      __builtin_amdgcn_global_load_lds(
          (const __attribute__((address_space(1))) void*)(bgp[i] + k0),
          (__attribute__((address_space(3))) void*)(Bs + (i * 256 + w * 64) * 8),
          16, 0, 0);
    __syncthreads();
#pragma unroll
    for (int kk = 0; kk < 2; kk++) {
      f16x8 af[4], bf[TN];
      int q = kk * 4 + quad;
#pragma unroll
      for (int i = 0; i < 4; i++) {
        int ra = wm + i * 16 + l16;
        af[i] = *(const f16x8*)&As[ra * 64 + (q ^ (ra & 7)) * 8];
      }
#pragma unroll
      for (int j = 0; j < TN; j++) {
        int rb = wn + j * 16 + l16;
        bf[j] = *(const f16x8*)&Bs[rb * 64 + (q ^ (rb & 7)) * 8];
      }
#pragma unroll
      for (int i = 0; i < 4; i++)
#pragma unroll
        for (int j = 0; j < TN; j++)
          acc[i][j] = __builtin_amdgcn_mfma_f32_16x16x32_f16(af[i], bf[j], acc[i][j], 0, 0, 0);
    }
  }

  if (MODE == 2) {
#pragma unroll
    for (int i = 0; i < 4; i++)
#pragma unroll
      for (int j = 0; j < TN; j++) {
        int col = n0 + wn + j * 16 + l16;
#pragma unroll
        for (int r = 0; r < 4; r++) {
          int row = m0 + wm + i * 16 + quad * 4 + r;
          po[(long)row * N + col] = acc[i][j][r];
        }
      }
  } else if (MODE == 6) {
#pragma unroll
    for (int i = 0; i < 4; i++)
#pragma unroll
      for (int j = 0; j < TN; j++) {
        int col = n0 + wn + j * 16 + l16;
#pragma unroll
        for (int r = 0; r < 4; r++) {
          int row = m0 + wm + i * 16 + quad * 4 + r;
          if (row < cnt) {
            int tok = ptok[poff + row];
            float scl = pw[poff + row];
            atomicAdd(&((float*)outp)[(long)tok * N + col], acc[i][j][r] * scl);
          }
        }
      }
  } else {
    const int ep = tile_n + 8;
    __syncthreads();
#pragma unroll
    for (int i = 0; i < 4; i++)
#pragma unroll
      for (int j = 0; j < TN; j++)
#pragma unroll
        for (int r = 0; r < 4; r++) {
          int lr = wm + i * 16 + quad * 4 + r;
          int lc = wn + j * 16 + l16;
          smem[lr * ep + lc] = (f16)acc[i][j][r];
        }
    __syncthreads();
    if (MODE == 5) {
      // act = silu(gate)*up : gate cols 0..63, up cols 64..127
#pragma unroll
      for (int ii = 0; ii < 4; ii++) {
        int c = ii * 256 + tid;
        int row = c >> 3, off = (c & 7) * 8;
        int grow = m0 + row;
        if (grow < cnt) {
          union { uint4 u; f16 h[8]; } ov;
#pragma unroll
          for (int jj = 0; jj < 8; jj++) {
            float g = (float)smem[row * ep + off + jj];
            float u = (float)smem[row * ep + 64 + off + jj];
            ov.h[jj] = (f16)(g / (1.0f + __expf(-g)) * u);
          }
          *(uint4*)&((f16*)outp)[(long)(poff + grow) * N + a0 + off] = ov.u;
        }
      }
    } else {
      const int cpr = tile_n / 8;
#pragma unroll
      for (int ii = 0; ii < 2 * TN; ii++) {
        int c = ii * 256 + tid;
        int row = c / cpr, off = (c % cpr) * 8;
        int grow = m0 + row;
        union { uint4 u; f16 h[8]; } sv;
        sv.u = *(const uint4*)&smem[row * ep + off];
        if (ROPE && n0 < 1280) {
          union { uint4 u; f16 h[8]; } pv;
          pv.u = *(const uint4*)&smem[row * ep + (off ^ 32)];
          int pos = pos_ids[grow];
          bool low = off < 32;
#pragma unroll
          for (int jj = 0; jj < 8; jj++) {
            int fi = (off & 31) + jj;
            float fr = (float)pos * __expf((float)fi * (-13.815510557964274f / 32.0f));
            float sn, cs;
            sincosf(fr, &sn, &cs);
            float x = (float)sv.h[jj], y = (float)pv.h[jj];
            sv.h[jj] = (f16)(low ? (x * cs - y * sn) : (x * cs + y * sn));
          }
        }
        *(uint4*)&((f16*)outp)[(long)grow * N + n0 + off] = sv.u;
      }
    }
  }
}

// ---------------------------------------------------------------------------
// V transpose: qkv v-section -> vT [B*NKV][64 d][1024 seq]
// ---------------------------------------------------------------------------
__global__ __launch_bounds__(256) void vtrans_kernel(const f16* __restrict__ qkv,
                                                     f16* __restrict__ vT) {
  int bk = blockIdx.x;
  int st = blockIdx.y;
  int b = bk >> 2, kvh = bk & 3;
  int s0 = st * 64;
  int tid = threadIdx.x;
#pragma unroll
  for (int i = 0; i < 2; i++) {
    int c = i * 256 + tid;
    int d = c & 63, sc = c >> 6;
    union { uint4 u; f16 h[8]; } v;
#pragma unroll
    for (int j = 0; j < 8; j++)
      v.h[j] = qkv[(long)(b * SEQ + s0 + sc * 8 + j) * 1536 + 1280 + kvh * 64 + d];
    *(uint4*)&vT[((long)bk * 64 + d) * 1024 + s0 + sc * 8] = v.u;
  }
}

// ---------------------------------------------------------------------------
// MFMA flash attention. grid (B*NH=32, S/64=16), block 256 (4 waves).
// KV staged in 128-row chunks (two 64-KV compute rounds per barrier pair).
// ---------------------------------------------------------------------------
__global__ __launch_bounds__(256) void attn_kernel(const f16* __restrict__ qkv,
                                                   const f16* __restrict__ vT,
                                                   f16* __restrict__ aout) {
  int bh = blockIdx.x;
  int b = bh >> 4, h = bh & 15;
  int kvh = h >> 2;
  int qt = blockIdx.y;
  int q0 = qt * 64;
  int tid = threadIdx.x;
  int w = tid >> 6, lane = tid & 63;
  int quad = lane >> 4, l16 = lane & 15;

  __shared__ f16 smem[24576];  // Qs[64][64] | Ks[128][64] | Vs[64][128] | Ps 4x1024
  f16* Qs = smem;
  f16* Ks = smem + 4096;
  f16* Vs = smem + 12288;
  f16* Psw = smem + 20480 + w * 1024;

#pragma unroll
  for (int i = 0; i < 2; i++) {
    int c = i * 256 + tid;
    int r = c >> 3;
    int kq = (c & 7) ^ (r & 7);
    __builtin_amdgcn_global_load_lds(
        (const __attribute__((address_space(1))) void*)(qkv + (long)(b * SEQ + q0 + r) * 1536 + h * 64 + kq * 8),
        (__attribute__((address_space(3))) void*)(Qs + c * 8), 16, 0, 0);
  }

  float mr[4], lsum[4];
  f32x4 oacc[4] = {};
#pragma unroll
  for (int r = 0; r < 4; r++) { mr[r] = -1e30f; lsum[r] = 0.f; }

  int nch = (qt + 2) >> 1;
  for (int ch = 0; ch < nch; ch++) {
    __syncthreads();
#pragma unroll
    for (int i = 0; i < 4; i++) {
      int c = i * 256 + tid;
      int r = c >> 3;
      int kq = (c & 7) ^ (r & 7);
      __builtin_amdgcn_global_load_lds(
          (const __attribute__((address_space(1))) void*)(qkv + (long)(b * SEQ + ch * 128 + r) * 1536 + 1024 + kvh * 64 + kq * 8),
          (__attribute__((address_space(3))) void*)(Ks + c * 8), 16, 0, 0);
    }
#pragma unroll
    for (int i = 0; i < 4; i++) {
      int c = i * 256 + tid;
      int d = c >> 4;
      int kq = (c & 15) ^ (d & 15);
      __builtin_amdgcn_global_load_lds(
          (const __attribute__((address_space(1))) void*)(vT + ((long)(b * 4 + kvh) * 64 + d) * 1024 + ch * 128 + kq * 8),
          (__attribute__((address_space(3))) void*)(Vs + c * 8), 16, 0, 0);
    }
    __syncthreads();

    for (int half = 0; half < 2; half++) {
      int kt = ch * 2 + half;
      if (kt > qt) break;

      int m = w * 16 + l16;
      f16x8 aq0 = *(const f16x8*)&Qs[m * 64 + ((quad) ^ (m & 7)) * 8];
      f16x8 aq1 = *(const f16x8*)&Qs[m * 64 + ((4 + quad) ^ (m & 7)) * 8];
      f32x4 sacc[4];
#pragma unroll
      for (int j = 0; j < 4; j++) {
        int n = half * 64 + j * 16 + l16;
        f16x8 bk0 = *(const f16x8*)&Ks[n * 64 + ((quad) ^ (n & 7)) * 8];
        f16x8 bk1 = *(const f16x8*)&Ks[n * 64 + ((4 + quad) ^ (n & 7)) * 8];
        f32x4 z = {};
        z = __builtin_amdgcn_mfma_f32_16x16x32_f16(aq0, bk0, z, 0, 0, 0);
        z = __builtin_amdgcn_mfma_f32_16x16x32_f16(aq1, bk1, z, 0, 0, 0);
        sacc[j] = z;
      }

      bool diag = (kt == qt);
      float sv[4][4];
      float rowmax[4];
#pragma unroll
      for (int r = 0; r < 4; r++) rowmax[r] = -1e30f;
#pragma unroll
      for (int j = 0; j < 4; j++)
#pragma unroll
        for (int r = 0; r < 4; r++) {
          float s = sacc[j][r] * 0.125f;
          if (diag && (j * 16 + l16 > w * 16 + quad * 4 + r)) s = -1e30f;
          sv[j][r] = s;
          rowmax[r] = fmaxf(rowmax[r], s);
        }
#pragma unroll
      for (int r = 0; r < 4; r++) {
        rowmax[r] = fmaxf(rowmax[r], __shfl_xor(rowmax[r], 1));
        rowmax[r] = fmaxf(rowmax[r], __shfl_xor(rowmax[r], 2));
        rowmax[r] = fmaxf(rowmax[r], __shfl_xor(rowmax[r], 4));
        rowmax[r] = fmaxf(rowmax[r], __shfl_xor(rowmax[r], 8));
      }
#pragma unroll
      for (int r = 0; r < 4; r++) {
        float mn = fmaxf(mr[r], rowmax[r]);
        float al = __expf(mr[r] - mn);
        mr[r] = mn;
        float rs = 0.f;
#pragma unroll
        for (int j = 0; j < 4; j++) {
          float pv = __expf(sv[j][r] - mn);
          sv[j][r] = pv;
          rs += pv;
        }
        rs += __shfl_xor(rs, 1);
        rs += __shfl_xor(rs, 2);
        rs += __shfl_xor(rs, 4);
        rs += __shfl_xor(rs, 8);
        lsum[r] = lsum[r] * al + rs;
#pragma unroll
        for (int j = 0; j < 4; j++) oacc[j][r] *= al;
      }

#pragma unroll
      for (int j = 0; j < 4; j++)
#pragma unroll
        for (int r = 0; r < 4; r++) {
          int row = quad * 4 + r;
          int chunk = j * 2 + (l16 >> 3);
          Psw[row * 64 + (chunk ^ (row & 7)) * 8 + (l16 & 7)] = (f16)sv[j][r];
        }

      f16x8 pf0 = *(const f16x8*)&Psw[l16 * 64 + ((quad) ^ (l16 & 7)) * 8];
      f16x8 pf1 = *(const f16x8*)&Psw[l16 * 64 + ((4 + quad) ^ (l16 & 7)) * 8];
#pragma unroll
      for (int j = 0; j < 4; j++) {
        int d = j * 16 + l16;
        f16x8 v0 = *(const f16x8*)&Vs[d * 128 + (((half * 8 + quad) ^ (d & 15))) * 8];
        f16x8 v1 = *(const f16x8*)&Vs[d * 128 + (((half * 8 + 4 + quad) ^ (d & 15))) * 8];
        oacc[j] = __builtin_amdgcn_mfma_f32_16x16x32_f16(pf0, v0, oacc[j], 0, 0, 0);
        oacc[j] = __builtin_amdgcn_mfma_f32_16x16x32_f16(pf1, v1, oacc[j], 0, 0, 0);
      }
    }
  }

  __syncthreads();
  f16* Os = smem;
  float iv[4];
#pragma unroll
  for (int r = 0; r < 4; r++) iv[r] = 1.0f / lsum[r];
#pragma unroll
  for (int j = 0; j < 4; j++)
#pragma unroll
    for (int r = 0; r < 4; r++)
      Os[(w * 16 + quad * 4 + r) * 72 + j * 16 + l16] = (f16)(oacc[j][r] * iv[r]);
  __syncthreads();
#pragma unroll
  for (int i = 0; i < 2; i++) {
    int c = i * 256 + tid;
    int row = c >> 3, off = (c & 7) * 8;
    uint4 v = *(const uint4*)&Os[row * 72 + off];
    *(uint4*)&aout[(long)(b * SEQ + q0 + row) * 1024 + h * 64 + off] = v;
  }
}

// ---------------------------------------------------------------------------
// router: full-f32 logits from resid (own RMS) -> softmax -> top2 + probs out
// also computes shared-expert gate sigmoid(x2.segw) -> pw[4096+t]
// ---------------------------------------------------------------------------
__global__ __launch_bounds__(256) void router_kernel(
    const float* __restrict__ resid, const float* __restrict__ ln2w,
    const float* __restrict__ rw, const float* __restrict__ segw,
    int* __restrict__ topi, float* __restrict__ topw,
    float* __restrict__ probs, float* __restrict__ pw_shared) {
  int t = blockIdx.x * 4 + (threadIdx.x >> 6);
  int lane = threadIdx.x & 63;
  const float* x = resid + (long)t * 1024;
  float ss = 0.f;
  for (int h = lane; h < 1024; h += 64) {
    float v = x[h];
    ss += v * v;
  }
  ss = wave_sum64(ss);
  float sc = rsqrtf(ss * (1.0f / 1024.0f) + 1e-6f);
  float acc[8] = {0.f, 0.f, 0.f, 0.f, 0.f, 0.f, 0.f, 0.f};
  float acc9 = 0.f;
  for (int h = lane; h < 1024; h += 64) {
    float xn = x[h] * sc * ln2w[h];
    const float4* r4 = (const float4*)(rw + h * 8);
    float4 ra = r4[0], rb = r4[1];
    acc[0] += xn * ra.x; acc[1] += xn * ra.y; acc[2] += xn * ra.z; acc[3] += xn * ra.w;
    acc[4] += xn * rb.x; acc[5] += xn * rb.y; acc[6] += xn * rb.z; acc[7] += xn * rb.w;
    acc9 += xn * segw[h];
  }
#pragma unroll
  for (int m = 1; m < 64; m <<= 1) {
#pragma unroll
    for (int e = 0; e < 8; e++) acc[e] += __shfl_xor(acc[e], m);
    acc9 += __shfl_xor(acc9, m);
  }
  if (lane == 0) {
    pw_shared[t] = 1.0f / (1.0f + expf(-acc9));
    float mx = acc[0];
#pragma unroll
    for (int e = 1; e < 8; e++) mx = fmaxf(mx, acc[e]);
    float p[8];
    float s = 0.f;
#pragma unroll
    for (int e = 0; e < 8; e++) {
      p[e] = expf(acc[e] - mx);
      s += p[e];
    }
    float inv = 1.0f / s;
#pragma unroll
    for (int e = 0; e < 8; e++) p[e] *= inv;
    float4 pa = {p[0], p[1], p[2], p[3]};
    float4 pb = {p[4], p[5], p[6], p[7]};
    *(float4*)(probs + t * 8) = pa;
    *(float4*)(probs + t * 8 + 4) = pb;
    int i1 = 0;
    float b1 = p[0];
#pragma unroll
    for (int e = 1; e < 8; e++)
      if (p[e] > b1) { b1 = p[e]; i1 = e; }
    int i2 = -1;
    float b2 = -1.f;
#pragma unroll
    for (int e = 0; e < 8; e++)
      if (e != i1 && p[e] > b2) { b2 = p[e]; i2 = e; }
    topi[2 * t] = i1;
    topi[2 * t + 1] = i2;
    topw[2 * t] = b1;
    topw[2 * t + 1] = b2;
  }
}

// ---------------------------------------------------------------------------
// compact pairs by expert (single block) + psum reduction + aux output.
// Fills segment 8 (shared expert): identity ptok rows 4096..6143.
// ---------------------------------------------------------------------------
__global__ __launch_bounds__(256) void compact_kernel(
    const int* __restrict__ topi, const float* __restrict__ topw, int* __restrict__ segc,
    int* __restrict__ sego, int* __restrict__ ptok, float* __restrict__ pw,
    const float* __restrict__ probs, float* __restrict__ aux_out) {
  __shared__ int c[8];
  __shared__ int off[9];
  __shared__ int cur[8];
  __shared__ float ps[4][8];
  int tid = threadIdx.x;
  if (tid < 8) { c[tid] = 0; cur[tid] = 0; }
  __syncthreads();
  for (int i = tid; i < 4096; i += 256) atomicAdd(&c[topi[i]], 1);
  for (int i = tid; i < 2048; i += 256) ptok[4096 + i] = i;

  float s8[8] = {0.f, 0.f, 0.f, 0.f, 0.f, 0.f, 0.f, 0.f};
  for (int i = tid; i < 2048; i += 256) {
    float4 a = *(const float4*)(probs + i * 8);
    float4 b = *(const float4*)(probs + i * 8 + 4);
    s8[0] += a.x; s8[1] += a.y; s8[2] += a.z; s8[3] += a.w;
    s8[4] += b.x; s8[5] += b.y; s8[6] += b.z; s8[7] += b.w;
  }
#pragma unroll
  for (int e = 0; e < 8; e++) s8[e] = wave_sum64(s8[e]);
  if ((tid & 63) == 0)
#pragma unroll
    for (int e = 0; e < 8; e++) ps[tid >> 6][e] = s8[e];
  __syncthreads();
  if (tid == 0) {
    off[0] = 0;
    for (int e = 0; e < 8; e++) off[e + 1] = off[e] + c[e];
    float a = 0.f;
    for (int e = 0; e < 8; e++) {
      float tot = ps[0][e] + ps[1][e] + ps[2][e] + ps[3][e];
      float d = tot * (1.0f / 2048.0f) - 0.125f;
      a += d * d;
    }
    aux_out[0] = a * (1.0f / 8.0f);
  }
  __syncthreads();
  for (int i = tid; i < 4096; i += 256) {
    int e = topi[i];
    int pidx = atomicAdd(&cur[e], 1);
    int slot = off[e] + pidx;
    ptok[slot] = i >> 1;
    pw[slot] = topw[i];
  }
  if (tid < 8) {
    segc[tid] = c[tid];
    sego[tid] = off[tid];
  }
  if (tid == 0) {
    segc[8] = 2048;
    sego[8] = 4096;
  }
}

// ---------------------------------------------------------------------------
extern "C" void kernel_launch(void* const* d_in, const int* in_sizes, int n_in,
                              void* d_out, int out_size, void* d_ws, size_t ws_size,
                              hipStream_t stream) {
  const float* hidden = (const float*)d_in[0];
  const int* pos_ids = (const int*)d_in[2];
  const float* ln1w = (const float*)d_in[3];
  const float* ln2w = (const float*)d_in[4];
  const float* wq = (const float*)d_in[5];
  const float* wk = (const float*)d_in[6];
  const float* wv = (const float*)d_in[7];
  const float* wo = (const float*)d_in[8];
  const float* router_w = (const float*)d_in[9];
  const float* egw = (const float*)d_in[10];
  const float* euw = (const float*)d_in[11];
  const float* edw = (const float*)d_in[12];
  const float* sgw = (const float*)d_in[13];
  const float* suw = (const float*)d_in[14];
  const float* sdw = (const float*)d_in[15];
  const float* segw = (const float*)d_in[16];
  float* out = (float*)d_out;

  char* p = (char*)d_ws;
  auto alloc = [&](size_t bytes) {
    char* r = p;
    p += (bytes + 255) & ~(size_t)255;
    return r;
  };
  f16* wqkvT = (f16*)alloc(1536l * 1024 * 2);
  f16* woT = (f16*)alloc(1024l * 1024 * 2);
  f16* guT = (f16*)alloc(9l * 2048 * 1024 * 2);   // experts 0-7 + shared(8)
  f16* dnT = (f16*)alloc(9l * 1024 * 1024 * 2);
  f16* xln1 = (f16*)alloc(2048l * 1024 * 2);
  f16* qkv = (f16*)alloc(2048l * 1536 * 2);
  f16* vT = (f16*)alloc(8l * 64 * 1024 * 2);
  f16* attnO = (f16*)alloc(2048l * 1024 * 2);
  float* wo_part = (float*)alloc(2l * 2048 * 1024 * 4);
  f16* x2 = (f16*)alloc(2048l * 1024 * 2);
  f16* act_all = (f16*)alloc(6144l * 1024 * 2);
  int* topi = (int*)alloc(4096 * 4);
  float* topw = (float*)alloc(4096 * 4);
  float* probs = (float*)alloc(2048l * 8 * 4);
  int* ptok = (int*)alloc(6144 * 4);
  float* pwts = (float*)alloc(6144 * 4);
  int* segc = (int*)alloc(9 * 4);
  int* sego = (int*)alloc(9 * 4);

  // weight transposes f32[K,N] -> f16[N,K]
  transpose_kernel<<<dim3(16, 16, 1), 256, 0, stream>>>(wq, wqkvT, 1024, 1024, 0, 0);
  transpose_kernel<<<dim3(4, 16, 1), 256, 0, stream>>>(wk, wqkvT + 1024l * 1024, 1024, 256, 0, 0);
  transpose_kernel<<<dim3(4, 16, 1), 256, 0, stream>>>(wv, wqkvT + 1280l * 1024, 1024, 256, 0, 0);
  transpose_kernel<<<dim3(16, 16, 1), 256, 0, stream>>>(wo, woT, 1024, 1024, 0, 0);
  transpose_kernel<<<dim3(16, 16, 8), 256, 0, stream>>>(egw, guT, 1024, 1024, 1024l * 1024, 2048l * 1024);
  transpose_kernel<<<dim3(16, 16, 8), 256, 0, stream>>>(euw, guT + 1024l * 1024, 1024, 1024, 1024l * 1024, 2048l * 1024);
  transpose_kernel<<<dim3(16, 16, 1), 256, 0, stream>>>(sgw, guT + 8l * 2048 * 1024, 1024, 1024, 0, 0);
  transpose_kernel<<<dim3(16, 16, 1), 256, 0, stream>>>(suw, guT + 8l * 2048 * 1024 + 1024l * 1024, 1024, 1024, 0, 0);
  transpose_kernel<<<dim3(16, 16, 8), 256, 0, stream>>>(edw, dnT, 1024, 1024, 1024l * 1024, 1024l * 1024);
  transpose_kernel<<<dim3(16, 16, 1), 256, 0, stream>>>(sdw, dnT + 8l * 1024 * 1024, 1024, 1024, 0, 0);

  // attention path (rope fused into QKV epilogue)
  rms_kernel<<<2048, 256, 0, stream>>>(hidden, ln1w, xln1);
  gemm_kernel<0, 2, 1><<<dim3(24, 16, 1), 256, 0, stream>>>(xln1, wqkvT, qkv, nullptr, nullptr, nullptr, nullptr, pos_ids, 1536, 1024, 0);
  vtrans_kernel<<<dim3(8, 16, 1), 256, 0, stream>>>(qkv, vT);
  attn_kernel<<<dim3(32, 16, 1), 256, 0, stream>>>(qkv, vT, attnO);
  // WO: K-split x2 into f32 partials; rms2 combines into OUT(resid) + x2
  gemm_kernel<2, 2, 0><<<dim3(16, 16, 2), 256, 0, stream>>>(attnO, woT, wo_part, nullptr, nullptr, nullptr, nullptr, nullptr, 1024, 1024, 2048l * 1024);
  rms2_kernel<<<2048, 256, 0, stream>>>(hidden, wo_part, wo_part + 2048l * 1024, ln2w, out, x2);

  // MoE path (shared expert = segment 8; its pw = sgate from router)
  router_kernel<<<512, 256, 0, stream>>>(out, ln2w, router_w, segw, topi, topw, probs, pwts + 4096);
  compact_kernel<<<1, 256, 0, stream>>>(topi, topw, segc, sego, ptok, pwts, probs, out + 2097152);

  gemm_kernel<5, 4, 0><<<dim3(16, 16, 9), 256, 0, stream>>>(x2, guT, act_all, ptok, nullptr, segc, sego, nullptr, 1024, 1024, 2048l * 1024);
  gemm_kernel<6, 2, 0><<<dim3(16, 16, 9), 256, 0, stream>>>(act_all, dnT, out, ptok, pwts, segc, sego, nullptr, 1024, 1024, 1024l * 1024);
}

// Round 6
// 374.641 us; speedup vs baseline: 3.4037x; 1.0749x over previous
//
#include <hip/hip_runtime.h>
#include <cstdint>
#include <cstddef>

typedef _Float16 f16;
typedef _Float16 f16x8 __attribute__((ext_vector_type(8)));
typedef float f32x4 __attribute__((ext_vector_type(4)));

#define SEQ 1024

// ---------------------------------------------------------------------------
// helpers
// ---------------------------------------------------------------------------
__device__ __forceinline__ float wave_sum64(float v) {
#pragma unroll
  for (int m = 1; m < 64; m <<= 1) v += __shfl_xor(v, m);
  return v;
}

// ---------------------------------------------------------------------------
// batched transpose f32 [K,N] -> f16 [N,K], all weights in ONE launch.
// Job table passed by value; 64x64 tiles; 16B/lane writes.
// ---------------------------------------------------------------------------
struct TJobs {
  const float* src[31];
  f16* dst[31];
  int K[31], N[31];
  int pre[32];
};

__global__ __launch_bounds__(256) void transb_kernel(TJobs a) {
  int bid = blockIdx.x;
  int job = 0;
  while (job < 30 && bid >= a.pre[job + 1]) job++;
  int t = bid - a.pre[job];
  const float* src = a.src[job];
  f16* dst = a.dst[job];
  int K = a.K[job], N = a.N[job];
  int ntn = N >> 6;
  int n0 = (t % ntn) * 64;
  int k0 = (t / ntn) * 64;
  __shared__ float tile[64][65];
  int tid = threadIdx.x;
#pragma unroll
  for (int i = 0; i < 4; i++) {
    int c = i * 256 + tid;
    int kr = c >> 4, cc = c & 15;
    float4 v = *(const float4*)(src + (long)(k0 + kr) * N + n0 + cc * 4);
    tile[kr][cc * 4 + 0] = v.x;
    tile[kr][cc * 4 + 1] = v.y;
    tile[kr][cc * 4 + 2] = v.z;
    tile[kr][cc * 4 + 3] = v.w;
  }
  __syncthreads();
#pragma unroll
  for (int i = 0; i < 2; i++) {
    int c = i * 256 + tid;
    int nr = c >> 3, kc = (c & 7) * 8;
    union { f16 h[8]; uint4 u; } cv;
#pragma unroll
    for (int jj = 0; jj < 8; jj++) cv.h[jj] = (f16)tile[kc + jj][nr];
    *(uint4*)(dst + (long)(n0 + nr) * K + k0 + kc) = cv.u;
  }
}

// ---------------------------------------------------------------------------
// RMSNorm: f32 [T,1024] -> f16 [T,1024]
// ---------------------------------------------------------------------------
__global__ __launch_bounds__(256) void rms_kernel(const float* __restrict__ x,
                                                  const float* __restrict__ w,
                                                  f16* __restrict__ out) {
  long t = blockIdx.x;
  int tid = threadIdx.x;
  float4 v = ((const float4*)(x + t * 1024))[tid];
  float ss = v.x * v.x + v.y * v.y + v.z * v.z + v.w * v.w;
  ss = wave_sum64(ss);
  __shared__ float sred[4];
  if ((tid & 63) == 0) sred[tid >> 6] = ss;
  __syncthreads();
  float tot = sred[0] + sred[1] + sred[2] + sred[3];
  float sc = rsqrtf(tot * (1.0f / 1024.0f) + 1e-6f);
  float4 wv = ((const float4*)w)[tid];
  union { f16 h[4]; uint2 u; } cv;
  cv.h[0] = (f16)(v.x * wv.x * sc);
  cv.h[1] = (f16)(v.y * wv.y * sc);
  cv.h[2] = (f16)(v.z * wv.z * sc);
  cv.h[3] = (f16)(v.w * wv.w * sc);
  *(uint2*)(out + t * 1024 + tid * 4) = cv.u;
}

// ---------------------------------------------------------------------------
// fused: resid = hidden + P1 + P2 -> OUT(f32); x2 = rms(resid)*w (f16);
// ALSO router: logits = xn . rw -> softmax -> top2/probs; sgate -> pw_shared.
// ---------------------------------------------------------------------------
__global__ __launch_bounds__(256) void rms2r_kernel(
    const float* __restrict__ hidden, const float* __restrict__ p1,
    const float* __restrict__ p2, const float* __restrict__ w,
    const float* __restrict__ rw, const float* __restrict__ segw,
    float* __restrict__ out_resid, f16* __restrict__ x2out,
    int* __restrict__ topi, float* __restrict__ topw,
    float* __restrict__ probs, float* __restrict__ pw_shared) {
  long t = blockIdx.x;
  int tid = threadIdx.x;
  float4 h = ((const float4*)(hidden + t * 1024))[tid];
  float4 a = ((const float4*)(p1 + t * 1024))[tid];
  float4 b = ((const float4*)(p2 + t * 1024))[tid];
  float4 v;
  v.x = h.x + a.x + b.x;
  v.y = h.y + a.y + b.y;
  v.z = h.z + a.z + b.z;
  v.w = h.w + a.w + b.w;
  ((float4*)(out_resid + t * 1024))[tid] = v;
  float ss = v.x * v.x + v.y * v.y + v.z * v.z + v.w * v.w;
  ss = wave_sum64(ss);
  __shared__ float sred[4];
  if ((tid & 63) == 0) sred[tid >> 6] = ss;
  __syncthreads();
  float tot = sred[0] + sred[1] + sred[2] + sred[3];
  float sc = rsqrtf(tot * (1.0f / 1024.0f) + 1e-6f);
  float4 wv = ((const float4*)w)[tid];
  float xa[4];
  xa[0] = v.x * wv.x * sc;
  xa[1] = v.y * wv.y * sc;
  xa[2] = v.z * wv.z * sc;
  xa[3] = v.w * wv.w * sc;
  union { f16 h[4]; uint2 u; } cv;
#pragma unroll
  for (int k = 0; k < 4; k++) cv.h[k] = (f16)xa[k];
  *(uint2*)(x2out + t * 1024 + tid * 4) = cv.u;

  // router logits
  float lacc[8] = {0.f, 0.f, 0.f, 0.f, 0.f, 0.f, 0.f, 0.f};
#pragma unroll
  for (int k = 0; k < 4; k++) {
    const float4* r4 = (const float4*)(rw + (tid * 4 + k) * 8);
    float4 ra = r4[0], rb = r4[1];
    float xk = xa[k];
    lacc[0] += xk * ra.x; lacc[1] += xk * ra.y; lacc[2] += xk * ra.z; lacc[3] += xk * ra.w;
    lacc[4] += xk * rb.x; lacc[5] += xk * rb.y; lacc[6] += xk * rb.z; lacc[7] += xk * rb.w;
  }
  float4 sg4 = ((const float4*)segw)[tid];
  float l9 = xa[0] * sg4.x + xa[1] * sg4.y + xa[2] * sg4.z + xa[3] * sg4.w;
#pragma unroll
  for (int m = 1; m < 64; m <<= 1) {
#pragma unroll
    for (int e = 0; e < 8; e++) lacc[e] += __shfl_xor(lacc[e], m);
    l9 += __shfl_xor(l9, m);
  }
  __shared__ float red[4][9];
  if ((tid & 63) == 0) {
#pragma unroll
    for (int e = 0; e < 8; e++) red[tid >> 6][e] = lacc[e];
    red[tid >> 6][8] = l9;
  }
  __syncthreads();
  if (tid == 0) {
    float p[8];
    float mx = -1e30f;
#pragma unroll
    for (int e = 0; e < 8; e++) {
      p[e] = red[0][e] + red[1][e] + red[2][e] + red[3][e];
      mx = fmaxf(mx, p[e]);
    }
    float l9t = red[0][8] + red[1][8] + red[2][8] + red[3][8];
    pw_shared[t] = 1.0f / (1.0f + expf(-l9t));
    float s = 0.f;
#pragma unroll
    for (int e = 0; e < 8; e++) {
      p[e] = expf(p[e] - mx);
      s += p[e];
    }
    float inv = 1.0f / s;
#pragma unroll
    for (int e = 0; e < 8; e++) p[e] *= inv;
    float4 pa = {p[0], p[1], p[2], p[3]};
    float4 pb = {p[4], p[5], p[6], p[7]};
    *(float4*)(probs + t * 8) = pa;
    *(float4*)(probs + t * 8 + 4) = pb;
    int i1 = 0;
    float b1 = p[0];
#pragma unroll
    for (int e = 1; e < 8; e++)
      if (p[e] > b1) { b1 = p[e]; i1 = e; }
    int i2 = -1;
    float b2 = -1.f;
#pragma unroll
    for (int e = 0; e < 8; e++)
      if (e != i1 && p[e] > b2) { b2 = p[e]; i2 = e; }
    topi[2 * t] = i1;
    topi[2 * t + 1] = i2;
    topw[2 * t] = b1;
    topw[2 * t + 1] = b2;
  }
}

// ---------------------------------------------------------------------------
// GEMM: C[M,N] = A[M,K] * BT[N,K]^T  (f16 in, f32 acc, MFMA 16x16x32)
// 256 threads (4 waves, 2x2), tile 128 x (32*TN), BK=64,
// global_load_lds(16B) staging with XOR-swizzled LDS placement.
// Epilogue LDS uses chunk-XOR swizzle (no padding) to stay at 32KB max.
// MODE 0: dense, f16 out; ROPE=1 applies rotary to cols < 1280 during store.
// MODE 2: dense, f32 out, K-split via blockIdx.z (out += z*estride)
// MODE 5: moe segment (z): A via ptok; B = 64 gate + 64 up rows; epilogue
//         act = silu(g)*u, f16 out rows poff+row (TN must be 4)
// MODE 6: moe segment (z): A rows direct; epilogue atomicAdd of acc*pw into
//         out[ptok[poff+row]*N + col] (f32)
// ---------------------------------------------------------------------------
template <int MODE, int TN, int ROPE>
__global__ __launch_bounds__(256) void gemm_kernel(
    const f16* __restrict__ A, const f16* __restrict__ BT, void* __restrict__ outp,
    const int* __restrict__ ptok, const float* __restrict__ pw,
    const int* __restrict__ segc, const int* __restrict__ sego,
    const int* __restrict__ pos_ids, int N, int K, long estride) {
  const int tile_n = 32 * TN;
  int n0 = blockIdx.x * tile_n;
  int a0 = blockIdx.x * 64;  // MODE5 act-col base
  int m0 = blockIdx.y * 128;
  int cnt = 1 << 30, poff = 0;
  int kbeg = 0, klen = K;
  float* po = (float*)outp;
  if (MODE >= 5) {
    int e = blockIdx.z;
    cnt = segc[e];
    poff = sego[e];
    if (cnt == 0 || m0 >= cnt) return;
    BT += (long)e * estride;
  } else if (MODE == 2) {
    klen = K / gridDim.z;
    kbeg = blockIdx.z * klen;
    po += (long)blockIdx.z * estride;
  }
  constexpr int STAGE = 8192 + 2048 * TN;
  constexpr int EPI = (MODE == 0 || MODE == 5) ? 128 * 32 * TN : 0;
  constexpr int SMEMN = STAGE > EPI ? STAGE : EPI;
  __shared__ f16 smem[SMEMN];
  f16* As = smem;
  f16* Bs = smem + 8192;
  int tid = threadIdx.x;
  int w = tid >> 6, lane = tid & 63;
  int quad = lane >> 4, l16 = lane & 15;
  int wm = (w >> 1) * 64, wn = (w & 1) * (TN * 16);

  const f16* agp[4];
  const f16* bgp[TN];
#pragma unroll
  for (int i = 0; i < 4; i++) {
    int c = i * 256 + tid;
    int r = c >> 3;
    int kq = (c & 7) ^ (r & 7);
    int ar = m0 + r;
    if (MODE == 5) {
      int rr = ar < cnt ? ar : cnt - 1;
      agp[i] = A + (long)ptok[poff + rr] * K + kq * 8;
    } else if (MODE == 6) {
      int rr = ar < cnt ? ar : cnt - 1;
      agp[i] = A + (long)(poff + rr) * K + kq * 8;
    } else {
      agp[i] = A + (long)ar * K + kq * 8;
    }
  }
#pragma unroll
  for (int i = 0; i < TN; i++) {
    int c = i * 256 + tid;
    int r = c >> 3;
    int kq = (c & 7) ^ (r & 7);
    long br;
    if (MODE == 5) br = (r < 64) ? (a0 + r) : (1024 + a0 + (r - 64));
    else br = n0 + r;
    bgp[i] = BT + br * K + kq * 8;
  }

  f32x4 acc[4][TN] = {};

  for (int k0 = kbeg; k0 < kbeg + klen; k0 += 64) {
    __syncthreads();
#pragma unroll
    for (int i = 0; i < 4; i++)
      __builtin_amdgcn_global_load_lds(
          (const __attribute__((address_space(1))) void*)(agp[i] + k0),
          (__attribute__((address_space(3))) void*)(As + (i * 256 + w * 64) * 8),
          16, 0, 0);
#pragma unroll
    for (int i = 0; i < TN; i++)
      __builtin_amdgcn_global_load_lds(
          (const __attribute__((address_space(1))) void*)(bgp[i] + k0),
          (__attribute__((address_space(3))) void*)(Bs + (i * 256 + w * 64) * 8),
          16, 0, 0);
    __syncthreads();
#pragma unroll
    for (int kk = 0; kk < 2; kk++) {
      f16x8 af[4], bf[TN];
      int q = kk * 4 + quad;
#pragma unroll
      for (int i = 0; i < 4; i++) {
        int ra = wm + i * 16 + l16;
        af[i] = *(const f16x8*)&As[ra * 64 + (q ^ (ra & 7)) * 8];
      }
#pragma unroll
      for (int j = 0; j < TN; j++) {
        int rb = wn + j * 16 + l16;
        bf[j] = *(const f16x8*)&Bs[rb * 64 + (q ^ (rb & 7)) * 8];
      }
#pragma unroll
      for (int i = 0; i < 4; i++)
#pragma unroll
        for (int j = 0; j < TN; j++)
          acc[i][j] = __builtin_amdgcn_mfma_f32_16x16x32_f16(af[i], bf[j], acc[i][j], 0, 0, 0);
    }
  }

  if (MODE == 2) {
#pragma unroll
    for (int i = 0; i < 4; i++)
#pragma unroll
      for (int j = 0; j < TN; j++) {
        int col = n0 + wn + j * 16 + l16;
#pragma unroll
        for (int r = 0; r < 4; r++) {
          int row = m0 + wm + i * 16 + quad * 4 + r;
          po[(long)row * N + col] = acc[i][j][r];
        }
      }
  } else if (MODE == 6) {
#pragma unroll
    for (int i = 0; i < 4; i++)
#pragma unroll
      for (int j = 0; j < TN; j++) {
        int col = n0 + wn + j * 16 + l16;
#pragma unroll
        for (int r = 0; r < 4; r++) {
          int row = m0 + wm + i * 16 + quad * 4 + r;
          if (row < cnt) {
            int tok = ptok[poff + row];
            float scl = pw[poff + row];
            atomicAdd(&((float*)outp)[(long)tok * N + col], acc[i][j][r] * scl);
          }
        }
      }
  } else {
    // epilogue via LDS with chunk-XOR swizzle (chunk' = chunk ^ (row&7))
    __syncthreads();
#pragma unroll
    for (int i = 0; i < 4; i++)
#pragma unroll
      for (int j = 0; j < TN; j++)
#pragma unroll
        for (int r = 0; r < 4; r++) {
          int lr = wm + i * 16 + quad * 4 + r;
          int lc = wn + j * 16 + l16;
          int sc_ = ((((lc >> 3) ^ (lr & 7)) << 3) | (lc & 7));
          smem[lr * tile_n + sc_] = (f16)acc[i][j][r];
        }
    __syncthreads();
    if (MODE == 5) {
      // act = silu(gate)*up : gate chunks 0..7, up chunks 8..15 per row
#pragma unroll
      for (int ii = 0; ii < 4; ii++) {
        int c = ii * 256 + tid;
        int row = c >> 3, ci = c & 7;
        int grow = m0 + row;
        if (grow < cnt) {
          int gci = ci ^ (row & 7);
          f16x8 gv = *(const f16x8*)&smem[row * 128 + gci * 8];
          f16x8 uv = *(const f16x8*)&smem[row * 128 + (gci + 8) * 8];
          union { uint4 u; f16 h[8]; } ov;
#pragma unroll
          for (int jj = 0; jj < 8; jj++) {
            float g = (float)gv[jj];
            float u = (float)uv[jj];
            ov.h[jj] = (f16)(g / (1.0f + __expf(-g)) * u);
          }
          *(uint4*)&((f16*)outp)[(long)(poff + grow) * N + a0 + ci * 8] = ov.u;
        }
      }
    } else {
      const int cpr = tile_n / 8;
#pragma unroll
      for (int ii = 0; ii < 2 * TN; ii++) {
        int c = ii * 256 + tid;
        int row = c / cpr, ci = c % cpr;
        int off = ci * 8;
        int grow = m0 + row;
        union { uint4 u; f16 h[8]; } sv;
        sv.u = *(const uint4*)&smem[row * tile_n + (ci ^ (row & 7)) * 8];
        if (ROPE && n0 < 1280) {
          union { uint4 u; f16 h[8]; } pv;
          pv.u = *(const uint4*)&smem[row * tile_n + ((ci ^ 4) ^ (row & 7)) * 8];
          int pos = pos_ids[grow];
          bool low = off < 32;
#pragma unroll
          for (int jj = 0; jj < 8; jj++) {
            int fi = (off & 31) + jj;
            float fr = (float)pos * __expf((float)fi * (-13.815510557964274f / 32.0f));
            float sn, cs;
            sincosf(fr, &sn, &cs);
            float x = (float)sv.h[jj], y = (float)pv.h[jj];
            sv.h[jj] = (f16)(low ? (x * cs - y * sn) : (x * cs + y * sn));
          }
        }
        *(uint4*)&((f16*)outp)[(long)grow * N + n0 + off] = sv.u;
      }
    }
  }
}

// ---------------------------------------------------------------------------
// V transpose: qkv v-section -> vT [B*NKV][64 d][1024 seq]
// ---------------------------------------------------------------------------
__global__ __launch_bounds__(256) void vtrans_kernel(const f16* __restrict__ qkv,
                                                     f16* __restrict__ vT) {
  int bk = blockIdx.x;
  int st = blockIdx.y;
  int b = bk >> 2, kvh = bk & 3;
  int s0 = st * 64;
  int tid = threadIdx.x;
#pragma unroll
  for (int i = 0; i < 2; i++) {
    int c = i * 256 + tid;
    int d = c & 63, sc = c >> 6;
    union { uint4 u; f16 h[8]; } v;
#pragma unroll
    for (int j = 0; j < 8; j++)
      v.h[j] = qkv[(long)(b * SEQ + s0 + sc * 8 + j) * 1536 + 1280 + kvh * 64 + d];
    *(uint4*)&vT[((long)bk * 64 + d) * 1024 + s0 + sc * 8] = v.u;
  }
}

// ---------------------------------------------------------------------------
// MFMA flash attention. grid (B*NH=32, S/64=16), block 256 (4 waves).
// KV staged in 128-row chunks (two 64-KV compute rounds per barrier pair).
// ---------------------------------------------------------------------------
__global__ __launch_bounds__(256) void attn_kernel(const f16* __restrict__ qkv,
                                                   const f16* __restrict__ vT,
                                                   f16* __restrict__ aout) {
  int bh = blockIdx.x;
  int b = bh >> 4, h = bh & 15;
  int kvh = h >> 2;
  int qt = blockIdx.y;
  int q0 = qt * 64;
  int tid = threadIdx.x;
  int w = tid >> 6, lane = tid & 63;
  int quad = lane >> 4, l16 = lane & 15;

  __shared__ f16 smem[24576];  // Qs[64][64] | Ks[128][64] | Vs[64][128] | Ps 4x1024
  f16* Qs = smem;
  f16* Ks = smem + 4096;
  f16* Vs = smem + 12288;
  f16* Psw = smem + 20480 + w * 1024;

#pragma unroll
  for (int i = 0; i < 2; i++) {
    int c = i * 256 + tid;
    int r = c >> 3;
    int kq = (c & 7) ^ (r & 7);
    __builtin_amdgcn_global_load_lds(
        (const __attribute__((address_space(1))) void*)(qkv + (long)(b * SEQ + q0 + r) * 1536 + h * 64 + kq * 8),
        (__attribute__((address_space(3))) void*)(Qs + c * 8), 16, 0, 0);
  }

  float mr[4], lsum[4];
  f32x4 oacc[4] = {};
#pragma unroll
  for (int r = 0; r < 4; r++) { mr[r] = -1e30f; lsum[r] = 0.f; }

  int nch = (qt + 2) >> 1;
  for (int ch = 0; ch < nch; ch++) {
    __syncthreads();
#pragma unroll
    for (int i = 0; i < 4; i++) {
      int c = i * 256 + tid;
      int r = c >> 3;
      int kq = (c & 7) ^ (r & 7);
      __builtin_amdgcn_global_load_lds(
          (const __attribute__((address_space(1))) void*)(qkv + (long)(b * SEQ + ch * 128 + r) * 1536 + 1024 + kvh * 64 + kq * 8),
          (__attribute__((address_space(3))) void*)(Ks + c * 8), 16, 0, 0);
    }
#pragma unroll
    for (int i = 0; i < 4; i++) {
      int c = i * 256 + tid;
      int d = c >> 4;
      int kq = (c & 15) ^ (d & 15);
      __builtin_amdgcn_global_load_lds(
          (const __attribute__((address_space(1))) void*)(vT + ((long)(b * 4 + kvh) * 64 + d) * 1024 + ch * 128 + kq * 8),
          (__attribute__((address_space(3))) void*)(Vs + c * 8), 16, 0, 0);
    }
    __syncthreads();

    for (int half = 0; half < 2; half++) {
      int kt = ch * 2 + half;
      if (kt > qt) break;

      int m = w * 16 + l16;
      f16x8 aq0 = *(const f16x8*)&Qs[m * 64 + ((quad) ^ (m & 7)) * 8];
      f16x8 aq1 = *(const f16x8*)&Qs[m * 64 + ((4 + quad) ^ (m & 7)) * 8];
      f32x4 sacc[4];
#pragma unroll
      for (int j = 0; j < 4; j++) {
        int n = half * 64 + j * 16 + l16;
        f16x8 bk0 = *(const f16x8*)&Ks[n * 64 + ((quad) ^ (n & 7)) * 8];
        f16x8 bk1 = *(const f16x8*)&Ks[n * 64 + ((4 + quad) ^ (n & 7)) * 8];
        f32x4 z = {};
        z = __builtin_amdgcn_mfma_f32_16x16x32_f16(aq0, bk0, z, 0, 0, 0);
        z = __builtin_amdgcn_mfma_f32_16x16x32_f16(aq1, bk1, z, 0, 0, 0);
        sacc[j] = z;
      }

      bool diag = (kt == qt);
      float sv[4][4];
      float rowmax[4];
#pragma unroll
      for (int r = 0; r < 4; r++) rowmax[r] = -1e30f;
#pragma unroll
      for (int j = 0; j < 4; j++)
#pragma unroll
        for (int r = 0; r < 4; r++) {
          float s = sacc[j][r] * 0.125f;
          if (diag && (j * 16 + l16 > w * 16 + quad * 4 + r)) s = -1e30f;
          sv[j][r] = s;
          rowmax[r] = fmaxf(rowmax[r], s);
        }
#pragma unroll
      for (int r = 0; r < 4; r++) {
        rowmax[r] = fmaxf(rowmax[r], __shfl_xor(rowmax[r], 1));
        rowmax[r] = fmaxf(rowmax[r], __shfl_xor(rowmax[r], 2));
        rowmax[r] = fmaxf(rowmax[r], __shfl_xor(rowmax[r], 4));
        rowmax[r] = fmaxf(rowmax[r], __shfl_xor(rowmax[r], 8));
      }
#pragma unroll
      for (int r = 0; r < 4; r++) {
        float mn = fmaxf(mr[r], rowmax[r]);
        float al = __expf(mr[r] - mn);
        mr[r] = mn;
        float rs = 0.f;
#pragma unroll
        for (int j = 0; j < 4; j++) {
          float pv = __expf(sv[j][r] - mn);
          sv[j][r] = pv;
          rs += pv;
        }
        rs += __shfl_xor(rs, 1);
        rs += __shfl_xor(rs, 2);
        rs += __shfl_xor(rs, 4);
        rs += __shfl_xor(rs, 8);
        lsum[r] = lsum[r] * al + rs;
#pragma unroll
        for (int j = 0; j < 4; j++) oacc[j][r] *= al;
      }

#pragma unroll
      for (int j = 0; j < 4; j++)
#pragma unroll
        for (int r = 0; r < 4; r++) {
          int row = quad * 4 + r;
          int chunk = j * 2 + (l16 >> 3);
          Psw[row * 64 + (chunk ^ (row & 7)) * 8 + (l16 & 7)] = (f16)sv[j][r];
        }

      f16x8 pf0 = *(const f16x8*)&Psw[l16 * 64 + ((quad) ^ (l16 & 7)) * 8];
      f16x8 pf1 = *(const f16x8*)&Psw[l16 * 64 + ((4 + quad) ^ (l16 & 7)) * 8];
#pragma unroll
      for (int j = 0; j < 4; j++) {
        int d = j * 16 + l16;
        f16x8 v0 = *(const f16x8*)&Vs[d * 128 + (((half * 8 + quad) ^ (d & 15))) * 8];
        f16x8 v1 = *(const f16x8*)&Vs[d * 128 + (((half * 8 + 4 + quad) ^ (d & 15))) * 8];
        oacc[j] = __builtin_amdgcn_mfma_f32_16x16x32_f16(pf0, v0, oacc[j], 0, 0, 0);
        oacc[j] = __builtin_amdgcn_mfma_f32_16x16x32_f16(pf1, v1, oacc[j], 0, 0, 0);
      }
    }
  }

  __syncthreads();
  f16* Os = smem;
  float iv[4];
#pragma unroll
  for (int r = 0; r < 4; r++) iv[r] = 1.0f / lsum[r];
#pragma unroll
  for (int j = 0; j < 4; j++)
#pragma unroll
    for (int r = 0; r < 4; r++)
      Os[(w * 16 + quad * 4 + r) * 72 + j * 16 + l16] = (f16)(oacc[j][r] * iv[r]);
  __syncthreads();
#pragma unroll
  for (int i = 0; i < 2; i++) {
    int c = i * 256 + tid;
    int row = c >> 3, off = (c & 7) * 8;
    uint4 v = *(const uint4*)&Os[row * 72 + off];
    *(uint4*)&aout[(long)(b * SEQ + q0 + row) * 1024 + h * 64 + off] = v;
  }
}

// ---------------------------------------------------------------------------
// compact pairs by expert (single block) + psum reduction + aux output.
// Fills segment 8 (shared expert): identity ptok rows 4096..6143.
// ---------------------------------------------------------------------------
__global__ __launch_bounds__(256) void compact_kernel(
    const int* __restrict__ topi, const float* __restrict__ topw, int* __restrict__ segc,
    int* __restrict__ sego, int* __restrict__ ptok, float* __restrict__ pw,
    const float* __restrict__ probs, float* __restrict__ aux_out) {
  __shared__ int c[8];
  __shared__ int off[9];
  __shared__ int cur[8];
  __shared__ float ps[4][8];
  int tid = threadIdx.x;
  if (tid < 8) { c[tid] = 0; cur[tid] = 0; }
  __syncthreads();
  for (int i = tid; i < 4096; i += 256) atomicAdd(&c[topi[i]], 1);
  for (int i = tid; i < 2048; i += 256) ptok[4096 + i] = i;

  float s8[8] = {0.f, 0.f, 0.f, 0.f, 0.f, 0.f, 0.f, 0.f};
  for (int i = tid; i < 2048; i += 256) {
    float4 a = *(const float4*)(probs + i * 8);
    float4 b = *(const float4*)(probs + i * 8 + 4);
    s8[0] += a.x; s8[1] += a.y; s8[2] += a.z; s8[3] += a.w;
    s8[4] += b.x; s8[5] += b.y; s8[6] += b.z; s8[7] += b.w;
  }
#pragma unroll
  for (int e = 0; e < 8; e++) s8[e] = wave_sum64(s8[e]);
  if ((tid & 63) == 0)
#pragma unroll
    for (int e = 0; e < 8; e++) ps[tid >> 6][e] = s8[e];
  __syncthreads();
  if (tid == 0) {
    off[0] = 0;
    for (int e = 0; e < 8; e++) off[e + 1] = off[e] + c[e];
    float a = 0.f;
    for (int e = 0; e < 8; e++) {
      float tot = ps[0][e] + ps[1][e] + ps[2][e] + ps[3][e];
      float d = tot * (1.0f / 2048.0f) - 0.125f;
      a += d * d;
    }
    aux_out[0] = a * (1.0f / 8.0f);
  }
  __syncthreads();
  for (int i = tid; i < 4096; i += 256) {
    int e = topi[i];
    int pidx = atomicAdd(&cur[e], 1);
    int slot = off[e] + pidx;
    ptok[slot] = i >> 1;
    pw[slot] = topw[i];
  }
  if (tid < 8) {
    segc[tid] = c[tid];
    sego[tid] = off[tid];
  }
  if (tid == 0) {
    segc[8] = 2048;
    sego[8] = 4096;
  }
}

// ---------------------------------------------------------------------------
extern "C" void kernel_launch(void* const* d_in, const int* in_sizes, int n_in,
                              void* d_out, int out_size, void* d_ws, size_t ws_size,
                              hipStream_t stream) {
  const float* hidden = (const float*)d_in[0];
  const int* pos_ids = (const int*)d_in[2];
  const float* ln1w = (const float*)d_in[3];
  const float* ln2w = (const float*)d_in[4];
  const float* wq = (const float*)d_in[5];
  const float* wk = (const float*)d_in[6];
  const float* wv = (const float*)d_in[7];
  const float* wo = (const float*)d_in[8];
  const float* router_w = (const float*)d_in[9];
  const float* egw = (const float*)d_in[10];
  const float* euw = (const float*)d_in[11];
  const float* edw = (const float*)d_in[12];
  const float* sgw = (const float*)d_in[13];
  const float* suw = (const float*)d_in[14];
  const float* sdw = (const float*)d_in[15];
  const float* segw = (const float*)d_in[16];
  float* out = (float*)d_out;

  char* p = (char*)d_ws;
  auto alloc = [&](size_t bytes) {
    char* r = p;
    p += (bytes + 255) & ~(size_t)255;
    return r;
  };
  f16* wqkvT = (f16*)alloc(1536l * 1024 * 2);
  f16* woT = (f16*)alloc(1024l * 1024 * 2);
  f16* guT = (f16*)alloc(9l * 2048 * 1024 * 2);   // experts 0-7 + shared(8)
  f16* dnT = (f16*)alloc(9l * 1024 * 1024 * 2);
  f16* xln1 = (f16*)alloc(2048l * 1024 * 2);
  f16* qkv = (f16*)alloc(2048l * 1536 * 2);
  f16* vT = (f16*)alloc(8l * 64 * 1024 * 2);
  f16* attnO = (f16*)alloc(2048l * 1024 * 2);
  float* wo_part = (float*)alloc(2l * 2048 * 1024 * 4);
  f16* x2 = (f16*)alloc(2048l * 1024 * 2);
  f16* act_all = (f16*)alloc(6144l * 1024 * 2);
  int* topi = (int*)alloc(4096 * 4);
  float* topw = (float*)alloc(4096 * 4);
  float* probs = (float*)alloc(2048l * 8 * 4);
  int* ptok = (int*)alloc(6144 * 4);
  float* pwts = (float*)alloc(6144 * 4);
  int* segc = (int*)alloc(9 * 4);
  int* sego = (int*)alloc(9 * 4);

  // ---- batched weight transposes (one launch) ----
  TJobs tj;
  int nj = 0, pre = 0;
  auto addjob = [&](const float* s, f16* d, int K, int N) {
    tj.src[nj] = s; tj.dst[nj] = d; tj.K[nj] = K; tj.N[nj] = N;
    tj.pre[nj] = pre;
    pre += (N >> 6) * (K >> 6);
    nj++;
  };
  addjob(wq, wqkvT, 1024, 1024);
  addjob(wk, wqkvT + 1024l * 1024, 1024, 256);
  addjob(wv, wqkvT + 1280l * 1024, 1024, 256);
  addjob(wo, woT, 1024, 1024);
  addjob(sgw, guT + 8l * 2048 * 1024, 1024, 1024);
  addjob(suw, guT + 8l * 2048 * 1024 + 1024l * 1024, 1024, 1024);
  addjob(sdw, dnT + 8l * 1024 * 1024, 1024, 1024);
  for (int e = 0; e < 8; e++) {
    addjob(egw + (long)e * 1024 * 1024, guT + (long)e * 2048 * 1024, 1024, 1024);
    addjob(euw + (long)e * 1024 * 1024, guT + (long)e * 2048 * 1024 + 1024l * 1024, 1024, 1024);
    addjob(edw + (long)e * 1024 * 1024, dnT + (long)e * 1024 * 1024, 1024, 1024);
  }
  tj.pre[nj] = pre;  // sentinel (nj == 31)
  transb_kernel<<<pre, 256, 0, stream>>>(tj);

  // attention path (rope fused into QKV epilogue)
  rms_kernel<<<2048, 256, 0, stream>>>(hidden, ln1w, xln1);
  gemm_kernel<0, 2, 1><<<dim3(24, 16, 1), 256, 0, stream>>>(xln1, wqkvT, qkv, nullptr, nullptr, nullptr, nullptr, pos_ids, 1536, 1024, 0);
  vtrans_kernel<<<dim3(8, 16, 1), 256, 0, stream>>>(qkv, vT);
  attn_kernel<<<dim3(32, 16, 1), 256, 0, stream>>>(qkv, vT, attnO);
  // WO: K-split x2 into f32 partials; rms2r combines into OUT(resid) + x2 + router
  gemm_kernel<2, 2, 0><<<dim3(16, 16, 2), 256, 0, stream>>>(attnO, woT, wo_part, nullptr, nullptr, nullptr, nullptr, nullptr, 1024, 1024, 2048l * 1024);
  rms2r_kernel<<<2048, 256, 0, stream>>>(hidden, wo_part, wo_part + 2048l * 1024, ln2w, router_w, segw, out, x2, topi, topw, probs, pwts + 4096);

  // MoE path (shared expert = segment 8; its pw = sgate from router)
  compact_kernel<<<1, 256, 0, stream>>>(topi, topw, segc, sego, ptok, pwts, probs, out + 2097152);

  gemm_kernel<5, 4, 0><<<dim3(16, 16, 9), 256, 0, stream>>>(x2, guT, act_all, ptok, nullptr, segc, sego, nullptr, 1024, 1024, 2048l * 1024);
  gemm_kernel<6, 2, 0><<<dim3(16, 16, 9), 256, 0, stream>>>(act_all, dnT, out, ptok, pwts, segc, sego, nullptr, 1024, 1024, 1024l * 1024);
}